// Round 7
// baseline (4315.208 us; speedup 1.0000x reference)
//
#include <hip/hip_runtime.h>
#include <math.h>

#define T_LEN 1024
#define D_MODEL 1024
#define NKV 4
#define REP 4
#define DH 64
#define NB 63
#define TOPN 8
#define KVD 256        // NKV*DH
#define LDIM2 1328     // virtual concatenated width without k_cmp

typedef __attribute__((ext_vector_type(8))) short bf16x8;
typedef __attribute__((ext_vector_type(4))) float f32x4;

__device__ __forceinline__ float gelu_exact(float x) {
    return 0.5f * x * (1.0f + erff(x * 0.70710678118654752f));
}
__device__ __forceinline__ float sigmoidf(float x) {
    return 1.0f / (1.0f + expf(-x));
}
__device__ __forceinline__ unsigned short f2bf(float f) {
    union { float f; unsigned int u; } v; v.f = f;
    unsigned int u = v.u;
    unsigned int r = (u + 0x7FFFu + ((u >> 16) & 1u)) >> 16;  // RNE
    return (unsigned short)r;
}

// ---------------------------------------------------------------------------
// bf16 MFMA GEMM over virtual concat of 6 projections (k_cmp excluded — it is
// recomputed in f32). 64x64 tile, BK=32, grid (21,16).
// ---------------------------------------------------------------------------
__global__ __launch_bounds__(256) void proj_gemm(
    const float* __restrict__ x,
    const float* __restrict__ gate_w, const float* __restrict__ gate_b,
    const float* __restrict__ wv_cmp,
    const float* __restrict__ wk_slc, const float* __restrict__ wv_slc,
    const float* __restrict__ wk_win, const float* __restrict__ wv_win,
    float* __restrict__ gates_lin,
    float* __restrict__ v_cmp,
    float* __restrict__ k_slc, float* __restrict__ v_slc,
    float* __restrict__ k_win, float* __restrict__ v_win)
{
    __shared__ unsigned short As[64][40];
    __shared__ unsigned short Bs[64][40];
    const int tid = threadIdx.x;
    const int lane = tid & 63;
    const int w = tid >> 6;
    const int n0 = blockIdx.x * 64;
    const int m0 = blockIdx.y * 64;

    const int srow = tid >> 2;
    const int sseg = tid & 3;
    const float* ga = x + (m0 + srow) * D_MODEL + sseg * 8;
    const float* gb;
    {
        int nn = n0 + srow;
        if (nn < 48)        gb = gate_w + nn * D_MODEL;
        else if (nn < 304)  gb = wv_cmp + (nn - 48) * D_MODEL;
        else if (nn < 560)  gb = wk_slc + (nn - 304) * D_MODEL;
        else if (nn < 816)  gb = wv_slc + (nn - 560) * D_MODEL;
        else if (nn < 1072) gb = wk_win + (nn - 816) * D_MODEL;
        else if (nn < 1328) gb = wv_win + (nn - 1072) * D_MODEL;
        else                gb = gate_w;   // dummy, masked at store
        gb += sseg * 8;
    }

    f32x4 acc[4] = {};
    const int arow = (w << 4) + (lane & 15);
    const int kk8  = (lane >> 4) * 8;

    for (int k0 = 0; k0 < D_MODEL; k0 += 32) {
        float4 a0 = *(const float4*)(ga + k0);
        float4 a1 = *(const float4*)(ga + k0 + 4);
        float4 b0 = *(const float4*)(gb + k0);
        float4 b1 = *(const float4*)(gb + k0 + 4);
        bf16x8 ap, bp;
        ap[0]=(short)f2bf(a0.x); ap[1]=(short)f2bf(a0.y); ap[2]=(short)f2bf(a0.z); ap[3]=(short)f2bf(a0.w);
        ap[4]=(short)f2bf(a1.x); ap[5]=(short)f2bf(a1.y); ap[6]=(short)f2bf(a1.z); ap[7]=(short)f2bf(a1.w);
        bp[0]=(short)f2bf(b0.x); bp[1]=(short)f2bf(b0.y); bp[2]=(short)f2bf(b0.z); bp[3]=(short)f2bf(b0.w);
        bp[4]=(short)f2bf(b1.x); bp[5]=(short)f2bf(b1.y); bp[6]=(short)f2bf(b1.z); bp[7]=(short)f2bf(b1.w);
        __syncthreads();
        *(bf16x8*)&As[srow][sseg * 8] = ap;
        *(bf16x8*)&Bs[srow][sseg * 8] = bp;
        __syncthreads();
        bf16x8 af = *(bf16x8*)&As[arow][kk8];
        #pragma unroll
        for (int j = 0; j < 4; ++j) {
            bf16x8 bfr = *(bf16x8*)&Bs[j * 16 + (lane & 15)][kk8];
            acc[j] = __builtin_amdgcn_mfma_f32_16x16x32_bf16(af, bfr, acc[j], 0, 0, 0);
        }
    }

    // C/D layout: col = lane&15, row = (lane>>4)*4 + reg  [m89-verified]
    #pragma unroll
    for (int j = 0; j < 4; ++j) {
        int col = n0 + j * 16 + (lane & 15);
        if (col >= LDIM2) continue;
        int rbase = m0 + (w << 4) + (lane >> 4) * 4;
        float* dst; int cc; int stride = 256; float badd = 0.0f;
        if (col < 48)        { dst = gates_lin; cc = col;        stride = 48; badd = gate_b[col]; }
        else if (col < 304)  { dst = v_cmp;     cc = col - 48;   }
        else if (col < 560)  { dst = k_slc;     cc = col - 304;  }
        else if (col < 816)  { dst = v_slc;     cc = col - 560;  }
        else if (col < 1072) { dst = k_win;     cc = col - 816;  }
        else                 { dst = v_win;     cc = col - 1072; }
        #pragma unroll
        for (int rg = 0; rg < 4; ++rg)
            dst[(rbase + rg) * stride + cc] = acc[j][rg] + badd;
    }
}

// ---------------------------------------------------------------------------
// f32 GEMM for k_cmp (selection-critical). Tile 64M x 16N, grid (16,16).
// ---------------------------------------------------------------------------
__global__ __launch_bounds__(256) void gemm_kcmp_f32(
    const float* __restrict__ A, const float* __restrict__ B,
    float* __restrict__ k_cmp)
{
    __shared__ float As[32][68];
    __shared__ float Bs[32][20];
    const int tid = threadIdx.x;
    const int tx = tid & 15, ty = tid >> 4;
    const int n0 = blockIdx.x * 16, m0 = blockIdx.y * 64;
    const int srow = tid >> 2, sseg = tid & 3;        // A: 64 rows x 8 floats
    const int srB  = tid >> 4, skB  = (tid & 15) * 2; // B: 16 rows x 2 floats
    const float* ga = A + (m0 + srow) * D_MODEL + sseg * 8;
    const float* gb = B + (n0 + srB) * D_MODEL + skB;

    float acc[4] = {};
    for (int k0 = 0; k0 < D_MODEL; k0 += 32) {
        float4 a0 = *(const float4*)(ga + k0);
        float4 a1 = *(const float4*)(ga + k0 + 4);
        float2 b0 = *(const float2*)(gb + k0);
        __syncthreads();
        As[sseg*8+0][srow]=a0.x; As[sseg*8+1][srow]=a0.y; As[sseg*8+2][srow]=a0.z; As[sseg*8+3][srow]=a0.w;
        As[sseg*8+4][srow]=a1.x; As[sseg*8+5][srow]=a1.y; As[sseg*8+6][srow]=a1.z; As[sseg*8+7][srow]=a1.w;
        Bs[skB][srB] = b0.x; Bs[skB+1][srB] = b0.y;
        __syncthreads();
        #pragma unroll
        for (int kk = 0; kk < 32; ++kk) {
            float4 a4 = *(const float4*)&As[kk][ty * 4];
            float b = Bs[kk][tx];
            acc[0] += a4.x * b; acc[1] += a4.y * b;
            acc[2] += a4.z * b; acc[3] += a4.w * b;
        }
    }
    #pragma unroll
    for (int i = 0; i < 4; ++i)
        k_cmp[(m0 + ty * 4 + i) * KVD + n0 + tx] = acc[i];
}

// ---------------------------------------------------------------------------
// Block summaries. grid (63,4,2). Padded 516-float segments (conflict-free).
// ---------------------------------------------------------------------------
__global__ __launch_bounds__(256) void nsa_summarize(
    const float* __restrict__ k_cmp, const float* __restrict__ v_cmp,
    const float* __restrict__ block_pos,
    const float* __restrict__ ck1_w, const float* __restrict__ ck1_b,
    const float* __restrict__ ck2_w, const float* __restrict__ ck2_b,
    const float* __restrict__ cv1_w, const float* __restrict__ cv1_b,
    const float* __restrict__ cv2_w, const float* __restrict__ cv2_b,
    float* __restrict__ ksum, float* __restrict__ vsum)
{
    const int n = blockIdx.x, k = blockIdx.y, which = blockIdx.z;
    const float* src = which ? v_cmp : k_cmp;
    const float* w1  = which ? cv1_w : ck1_w;
    const float* b1  = which ? cv1_b : ck1_b;
    const float* w2  = which ? cv2_w : ck2_w;
    const float* b2  = which ? cv2_b : ck2_b;
    float* dst       = which ? vsum  : ksum;

    __shared__ float flat[4 * 516];
    __shared__ float hidden[DH];
    const int tid = threadIdx.x;
    const int start = n * 16;

    for (int e = tid; e < 512; e += 256) {
        int p = e >> 4, d4 = e & 15;
        float4 s = *(const float4*)(src + ((start + p) * NKV + k) * DH + d4 * 4);
        float4 bp = *(const float4*)(block_pos + p * DH + d4 * 4);
        float4 r; r.x = s.x + bp.x; r.y = s.y + bp.y; r.z = s.z + bp.z; r.w = s.w + bp.w;
        *(float4*)&flat[(p >> 3) * 516 + (p & 7) * 64 + d4 * 4] = r;
    }
    __syncthreads();
    {
        int h = tid >> 2, part = tid & 3;
        const float* wr = w1 + h * 2048 + part * 512;
        const float* fl = flat + part * 516;
        float s = 0.0f;
        for (int j = 0; j < 512; j += 4) {
            float4 a = *(const float4*)(fl + j);
            float4 b = *(const float4*)(wr + j);
            s += a.x * b.x + a.y * b.y + a.z * b.z + a.w * b.w;
        }
        s += __shfl_xor(s, 1);
        s += __shfl_xor(s, 2);
        if (part == 0) hidden[h] = gelu_exact(s + b1[h]);
    }
    __syncthreads();
    {
        int dh = tid >> 2, part = tid & 3;
        const float* wr = w2 + dh * 64 + part * 16;
        float s = 0.0f;
        #pragma unroll
        for (int hh = 0; hh < 16; ++hh) s += hidden[part * 16 + hh] * wr[hh];
        s += __shfl_xor(s, 1);
        s += __shfl_xor(s, 2);
        if (part == 0) dst[(n * NKV + k) * DH + dh] = s + b2[dh];
    }
}

// ---------------------------------------------------------------------------
// Fused attention. Broadcast transport for q / softmax weights via __shfl
// (v_readlane, SALU pipe) instead of LDS. CRITICAL CDNA RULE (round-6 bug):
// __shfl = ds_bpermute reads return 0 from EXEC-inactive source lanes, so
// every __shfl here runs with ALL 64 lanes active; masks applied afterward.
// ---------------------------------------------------------------------------
__global__ __launch_bounds__(256) void nsa_fused(
    const float* __restrict__ q,         // (16, T, 64)
    const float* __restrict__ gates_lin, // (T, 48)  pre-sigmoid
    const float* __restrict__ ksum,      // (63, 4, 64)
    const float* __restrict__ vsum,
    const float* __restrict__ k_slc,     // (T, 4, 64)
    const float* __restrict__ v_slc,
    const float* __restrict__ k_win,
    const float* __restrict__ v_win,
    float* __restrict__ out)             // (16, T, 64)
{
    const int t = blockIdx.x;
    const int k = blockIdx.y;
    const int tid = threadIdx.x;
    const int lane = tid & 63;
    const int r = tid >> 6;

    __shared__ float chunk[64][66];
    __shared__ float p_cmp_s[REP][64];
    __shared__ int   sel_s[TOPN];

    // q: one register per lane; q_d broadcast via readlane in score loops
    const float qreg = q[((r * NKV + k) * T_LEN + t) * DH + lane];

    // ---- compressed branch: stage ksum, scores (f32, selection-critical) ----
    for (int e = tid; e < 64 * 32; e += 256) {
        int p = e >> 5, d2 = e & 31;
        int nn = (p < NB) ? p : NB - 1;
        *(float2*)&chunk[p][d2 * 2] = *(const float2*)(ksum + (nn * NKV + k) * DH + d2 * 2);
    }
    __syncthreads();
    // compute dot for ALL lanes (no divergence around __shfl); mask after.
    float s;
    {
        float a0 = 0.0f, a1 = 0.0f;
        #pragma unroll
        for (int d2 = 0; d2 < 32; d2 += 2) {
            float2 c0 = *(const float2*)&chunk[lane][d2 * 2];
            float2 c1 = *(const float2*)&chunk[lane][d2 * 2 + 2];
            a0 += __shfl(qreg, d2 * 2)     * c0.x + __shfl(qreg, d2 * 2 + 1) * c0.y;
            a1 += __shfl(qreg, d2 * 2 + 2) * c1.x + __shfl(qreg, d2 * 2 + 3) * c1.y;
        }
        bool ok = (lane < NB) && ((lane * 16 + 31) <= t);
        s = ok ? (a0 + a1) * 0.125f : -1e30f;
    }
    float m = s;
    for (int off = 32; off; off >>= 1) m = fmaxf(m, __shfl_xor(m, off));
    float ex = (lane < NB) ? expf(s - m) : 0.0f;
    float sum = ex;
    for (int off = 32; off; off >>= 1) sum += __shfl_xor(sum, off);
    p_cmp_s[r][lane] = ex / sum;   // lane 63 -> 0
    __syncthreads();

    // ---- top-8 (wave 0), stable tie-break on lower index ----
    if (r == 0) {
        float imp = (lane < NB)
            ? (p_cmp_s[0][lane] + p_cmp_s[1][lane] + p_cmp_s[2][lane] + p_cmp_s[3][lane])
            : -1e30f;
        for (int it = 0; it < TOPN; ++it) {
            float v = imp; int i = lane;
            for (int off = 32; off; off >>= 1) {
                float ov = __shfl_xor(v, off);
                int   oi = __shfl_xor(i, off);
                if (ov > v || (ov == v && oi < i)) { v = ov; i = oi; }
            }
            if (lane == 0) sel_s[it] = i;
            if (lane == i) imp = -1e30f;
        }
    }
    __syncthreads();

    // ---- out_cmp: lane = d, weights from p_cmp_s (global vsum reads) ----
    float ocmp = 0.0f;
    if (t >= 31) {
        #pragma unroll 4
        for (int n = 0; n < NB; ++n)
            ocmp += p_cmp_s[r][n] * vsum[(n * NKV + k) * DH + lane];
    }

    // ================= selected branch =================
    float ssel[4];
    #pragma unroll
    for (int c = 0; c < 4; ++c) {
        __syncthreads();
        for (int e = tid; e < 64 * 32; e += 256) {
            int pidx = e >> 5, d2 = e & 31;
            int j = c * 64 + pidx;
            int pos = sel_s[j >> 5] * 16 + (j & 31);
            *(float2*)&chunk[pidx][d2 * 2] =
                *(const float2*)&k_slc[(pos * NKV + k) * DH + d2 * 2];
        }
        __syncthreads();
        int j = c * 64 + lane;
        int pos = sel_s[j >> 5] * 16 + (j & 31);
        float a0 = 0.0f, a1 = 0.0f;
        #pragma unroll
        for (int d2 = 0; d2 < 32; d2 += 2) {
            float2 c0 = *(const float2*)&chunk[lane][d2 * 2];
            float2 c1 = *(const float2*)&chunk[lane][d2 * 2 + 2];
            a0 += __shfl(qreg, d2 * 2)     * c0.x + __shfl(qreg, d2 * 2 + 1) * c0.y;
            a1 += __shfl(qreg, d2 * 2 + 2) * c1.x + __shfl(qreg, d2 * 2 + 3) * c1.y;
        }
        ssel[c] = (pos <= t) ? (a0 + a1) * 0.125f : -1e30f;
    }
    // register softmax over 256 (4 per lane)
    float psel[4];
    {
        float mx = fmaxf(fmaxf(ssel[0], ssel[1]), fmaxf(ssel[2], ssel[3]));
        for (int off = 32; off; off >>= 1) mx = fmaxf(mx, __shfl_xor(mx, off));
        float e0 = expf(ssel[0] - mx), e1 = expf(ssel[1] - mx);
        float e2 = expf(ssel[2] - mx), e3 = expf(ssel[3] - mx);
        float sm = e0 + e1 + e2 + e3;
        for (int off = 32; off; off >>= 1) sm += __shfl_xor(sm, off);
        float inv = 1.0f / sm;
        psel[0] = e0 * inv; psel[1] = e1 * inv; psel[2] = e2 * inv; psel[3] = e3 * inv;
    }
    float oslc = 0.0f;
    #pragma unroll
    for (int c = 0; c < 4; ++c) {
        __syncthreads();
        for (int e = tid; e < 64 * 32; e += 256) {
            int pidx = e >> 5, d2 = e & 31;
            int j = c * 64 + pidx;
            int pos = sel_s[j >> 5] * 16 + (j & 31);
            *(float2*)&chunk[pidx][d2 * 2] =
                *(const float2*)&v_slc[(pos * NKV + k) * DH + d2 * 2];
        }
        __syncthreads();
        float pv = psel[c];
        float a0 = 0.0f, a1 = 0.0f;
        #pragma unroll
        for (int j = 0; j < 64; j += 2) {
            a0 += __shfl(pv, j)     * chunk[j][lane];
            a1 += __shfl(pv, j + 1) * chunk[j + 1][lane];
        }
        oslc += a0 + a1;
    }

    // ================= sliding-window branch =================
    const int j0 = (t >= 255) ? (t - 255) : 0;
    const int W = t - j0 + 1;
    float swin[4];
    #pragma unroll
    for (int c = 0; c < 4; ++c) {
        __syncthreads();
        for (int e = tid; e < 64 * 32; e += 256) {
            int pidx = e >> 5, d2 = e & 31;
            int pos = j0 + c * 64 + pidx;
            *(float2*)&chunk[pidx][d2 * 2] =
                *(const float2*)&k_win[(pos * NKV + k) * DH + d2 * 2];
        }
        __syncthreads();
        int jj = c * 64 + lane;
        float a0 = 0.0f, a1 = 0.0f;
        #pragma unroll
        for (int d2 = 0; d2 < 32; d2 += 2) {
            float2 c0 = *(const float2*)&chunk[lane][d2 * 2];
            float2 c1 = *(const float2*)&chunk[lane][d2 * 2 + 2];
            a0 += __shfl(qreg, d2 * 2)     * c0.x + __shfl(qreg, d2 * 2 + 1) * c0.y;
            a1 += __shfl(qreg, d2 * 2 + 2) * c1.x + __shfl(qreg, d2 * 2 + 3) * c1.y;
        }
        swin[c] = (jj < W) ? (a0 + a1) * 0.125f : -1e30f;
    }
    float pwin[4];
    {
        float mx = fmaxf(fmaxf(swin[0], swin[1]), fmaxf(swin[2], swin[3]));
        for (int off = 32; off; off >>= 1) mx = fmaxf(mx, __shfl_xor(mx, off));
        float e0 = expf(swin[0] - mx), e1 = expf(swin[1] - mx);
        float e2 = expf(swin[2] - mx), e3 = expf(swin[3] - mx);
        float sm = e0 + e1 + e2 + e3;
        for (int off = 32; off; off >>= 1) sm += __shfl_xor(sm, off);
        float inv = 1.0f / sm;
        pwin[0] = e0 * inv; pwin[1] = e1 * inv; pwin[2] = e2 * inv; pwin[3] = e3 * inv;
    }
    float owin = 0.0f;
    #pragma unroll
    for (int c = 0; c < 4; ++c) {
        __syncthreads();
        for (int e = tid; e < 64 * 32; e += 256) {
            int pidx = e >> 5, d2 = e & 31;
            int pos = j0 + c * 64 + pidx;
            *(float2*)&chunk[pidx][d2 * 2] =
                *(const float2*)&v_win[(pos * NKV + k) * DH + d2 * 2];
        }
        __syncthreads();
        float pv = pwin[c];
        float a0 = 0.0f, a1 = 0.0f;
        #pragma unroll
        for (int j = 0; j < 64; j += 2) {
            a0 += __shfl(pv, j)     * chunk[j][lane];
            a1 += __shfl(pv, j + 1) * chunk[j + 1][lane];
        }
        owin += a0 + a1;
    }

    // ---- gating + write (lane = d) ----
    const int hq = r * NKV + k;
    const float* gl = gates_lin + t * 48 + hq * 3;
    float g0 = sigmoidf(gl[0]);
    float g1 = sigmoidf(gl[1]);
    float g2 = sigmoidf(gl[2]);
    out[(hq * T_LEN + t) * DH + lane] = g0 * ocmp + g1 * oslc + g2 * owin;
}

extern "C" void kernel_launch(void* const* d_in, const int* in_sizes, int n_in,
                              void* d_out, int out_size, void* d_ws, size_t ws_size,
                              hipStream_t stream) {
    const float* x         = (const float*)d_in[0];
    const float* q         = (const float*)d_in[1];
    const float* gate_w    = (const float*)d_in[2];
    const float* gate_b    = (const float*)d_in[3];
    const float* wk_cmp    = (const float*)d_in[4];
    const float* wv_cmp    = (const float*)d_in[5];
    const float* wk_slc    = (const float*)d_in[6];
    const float* wv_slc    = (const float*)d_in[7];
    const float* wk_win    = (const float*)d_in[8];
    const float* wv_win    = (const float*)d_in[9];
    const float* block_pos = (const float*)d_in[10];
    const float* ck1_w     = (const float*)d_in[11];
    const float* ck1_b     = (const float*)d_in[12];
    const float* ck2_w     = (const float*)d_in[13];
    const float* ck2_b     = (const float*)d_in[14];
    const float* cv1_w     = (const float*)d_in[15];
    const float* cv1_b     = (const float*)d_in[16];
    const float* cv2_w     = (const float*)d_in[17];
    const float* cv2_b     = (const float*)d_in[18];
    float* out = (float*)d_out;

    float* ws = (float*)d_ws;
    float* gates_lin = ws;                         // 1024*48
    float* k_cmp = gates_lin + T_LEN * 48;         // 1024*256 each
    float* v_cmp = k_cmp + T_LEN * KVD;
    float* k_slc = v_cmp + T_LEN * KVD;
    float* v_slc = k_slc + T_LEN * KVD;
    float* k_win = v_slc + T_LEN * KVD;
    float* v_win = k_win + T_LEN * KVD;
    float* ksum  = v_win + T_LEN * KVD;            // 63*4*64 each
    float* vsum  = ksum + NB * KVD;

    dim3 blk(256);
    proj_gemm<<<dim3(21, 16), blk, 0, stream>>>(
        x, gate_w, gate_b, wv_cmp, wk_slc, wv_slc, wk_win, wv_win,
        gates_lin, v_cmp, k_slc, v_slc, k_win, v_win);
    gemm_kcmp_f32<<<dim3(16, 16), blk, 0, stream>>>(x, wk_cmp, k_cmp);
    nsa_summarize<<<dim3(NB, NKV, 2), blk, 0, stream>>>(
        k_cmp, v_cmp, block_pos,
        ck1_w, ck1_b, ck2_w, ck2_b, cv1_w, cv1_b, cv2_w, cv2_b,
        ksum, vsum);
    nsa_fused<<<dim3(T_LEN, NKV), blk, 0, stream>>>(
        q, gates_lin, ksum, vsum, k_slc, v_slc, k_win, v_win, out);
}

// Round 8
// 387.455 us; speedup vs baseline: 11.1373x; 11.1373x over previous
//
#include <hip/hip_runtime.h>
#include <hip/hip_bf16.h>
#include <math.h>

#define T_LEN 1024
#define D_MODEL 1024
#define NKV 4
#define REP 4
#define DH 64
#define NB 63
#define TOPN 8
#define KVD 256        // NKV*DH
#define LDIM2 1328     // virtual concatenated width without k_cmp

typedef __attribute__((ext_vector_type(8))) short bf16x8;
typedef __attribute__((ext_vector_type(4))) float f32x4;

__device__ __forceinline__ float gelu_exact(float x) {
    return 0.5f * x * (1.0f + erff(x * 0.70710678118654752f));
}
__device__ __forceinline__ float sigmoidf(float x) {
    return 1.0f / (1.0f + expf(-x));
}
// pack 8 f32 -> 8 bf16 via HW v_cvt_pk_bf16_f32 (RNE), 4 instrs instead of ~40
__device__ __forceinline__ bf16x8 cvt8(float4 a0, float4 a1) {
    union { __hip_bfloat162 v; short2 s; } u0, u1, u2, u3;
    u0.v = __float22bfloat162_rn(make_float2(a0.x, a0.y));
    u1.v = __float22bfloat162_rn(make_float2(a0.z, a0.w));
    u2.v = __float22bfloat162_rn(make_float2(a1.x, a1.y));
    u3.v = __float22bfloat162_rn(make_float2(a1.z, a1.w));
    bf16x8 r;
    r[0] = u0.s.x; r[1] = u0.s.y; r[2] = u1.s.x; r[3] = u1.s.y;
    r[4] = u2.s.x; r[5] = u2.s.y; r[6] = u3.s.x; r[7] = u3.s.y;
    return r;
}

// ---------------------------------------------------------------------------
// bf16 MFMA GEMM over virtual concat of 6 projections (k_cmp excluded — it is
// recomputed in f32). 64x64 tile, BK=32, grid (21,16).
// ---------------------------------------------------------------------------
__global__ __launch_bounds__(256) void proj_gemm(
    const float* __restrict__ x,
    const float* __restrict__ gate_w, const float* __restrict__ gate_b,
    const float* __restrict__ wv_cmp,
    const float* __restrict__ wk_slc, const float* __restrict__ wv_slc,
    const float* __restrict__ wk_win, const float* __restrict__ wv_win,
    float* __restrict__ gates_lin,
    float* __restrict__ v_cmp,
    float* __restrict__ k_slc, float* __restrict__ v_slc,
    float* __restrict__ k_win, float* __restrict__ v_win)
{
    __shared__ unsigned short As[64][40];
    __shared__ unsigned short Bs[64][40];
    const int tid = threadIdx.x;
    const int lane = tid & 63;
    const int w = tid >> 6;
    const int n0 = blockIdx.x * 64;
    const int m0 = blockIdx.y * 64;

    const int srow = tid >> 2;
    const int sseg = tid & 3;
    const float* ga = x + (m0 + srow) * D_MODEL + sseg * 8;
    const float* gb;
    {
        int nn = n0 + srow;
        if (nn < 48)        gb = gate_w + nn * D_MODEL;
        else if (nn < 304)  gb = wv_cmp + (nn - 48) * D_MODEL;
        else if (nn < 560)  gb = wk_slc + (nn - 304) * D_MODEL;
        else if (nn < 816)  gb = wv_slc + (nn - 560) * D_MODEL;
        else if (nn < 1072) gb = wk_win + (nn - 816) * D_MODEL;
        else if (nn < 1328) gb = wv_win + (nn - 1072) * D_MODEL;
        else                gb = gate_w;   // dummy, masked at store
        gb += sseg * 8;
    }

    f32x4 acc[4] = {};
    const int arow = (w << 4) + (lane & 15);
    const int kk8  = (lane >> 4) * 8;

    for (int k0 = 0; k0 < D_MODEL; k0 += 32) {
        float4 a0 = *(const float4*)(ga + k0);
        float4 a1 = *(const float4*)(ga + k0 + 4);
        float4 b0 = *(const float4*)(gb + k0);
        float4 b1 = *(const float4*)(gb + k0 + 4);
        bf16x8 ap = cvt8(a0, a1);
        bf16x8 bp = cvt8(b0, b1);
        __syncthreads();
        *(bf16x8*)&As[srow][sseg * 8] = ap;
        *(bf16x8*)&Bs[srow][sseg * 8] = bp;
        __syncthreads();
        bf16x8 af = *(bf16x8*)&As[arow][kk8];
        #pragma unroll
        for (int j = 0; j < 4; ++j) {
            bf16x8 bfr = *(bf16x8*)&Bs[j * 16 + (lane & 15)][kk8];
            acc[j] = __builtin_amdgcn_mfma_f32_16x16x32_bf16(af, bfr, acc[j], 0, 0, 0);
        }
    }

    // C/D layout: col = lane&15, row = (lane>>4)*4 + reg  [m89-verified]
    #pragma unroll
    for (int j = 0; j < 4; ++j) {
        int col = n0 + j * 16 + (lane & 15);
        if (col >= LDIM2) continue;
        int rbase = m0 + (w << 4) + (lane >> 4) * 4;
        float* dst; int cc; int stride = 256; float badd = 0.0f;
        if (col < 48)        { dst = gates_lin; cc = col;        stride = 48; badd = gate_b[col]; }
        else if (col < 304)  { dst = v_cmp;     cc = col - 48;   }
        else if (col < 560)  { dst = k_slc;     cc = col - 304;  }
        else if (col < 816)  { dst = v_slc;     cc = col - 560;  }
        else if (col < 1072) { dst = k_win;     cc = col - 816;  }
        else                 { dst = v_win;     cc = col - 1072; }
        #pragma unroll
        for (int rg = 0; rg < 4; ++rg)
            dst[(rbase + rg) * stride + cc] = acc[j][rg] + badd;
    }
}

// ---------------------------------------------------------------------------
// f32 GEMM for k_cmp (selection-critical). Tile 64M x 16N, grid (16,16).
// ---------------------------------------------------------------------------
__global__ __launch_bounds__(256) void gemm_kcmp_f32(
    const float* __restrict__ A, const float* __restrict__ B,
    float* __restrict__ k_cmp)
{
    __shared__ float As[32][68];
    __shared__ float Bs[32][20];
    const int tid = threadIdx.x;
    const int tx = tid & 15, ty = tid >> 4;
    const int n0 = blockIdx.x * 16, m0 = blockIdx.y * 64;
    const int srow = tid >> 2, sseg = tid & 3;        // A: 64 rows x 8 floats
    const int srB  = tid >> 4, skB  = (tid & 15) * 2; // B: 16 rows x 2 floats
    const float* ga = A + (m0 + srow) * D_MODEL + sseg * 8;
    const float* gb = B + (n0 + srB) * D_MODEL + skB;

    float acc[4] = {};
    for (int k0 = 0; k0 < D_MODEL; k0 += 32) {
        float4 a0 = *(const float4*)(ga + k0);
        float4 a1 = *(const float4*)(ga + k0 + 4);
        float2 b0 = *(const float2*)(gb + k0);
        __syncthreads();
        As[sseg*8+0][srow]=a0.x; As[sseg*8+1][srow]=a0.y; As[sseg*8+2][srow]=a0.z; As[sseg*8+3][srow]=a0.w;
        As[sseg*8+4][srow]=a1.x; As[sseg*8+5][srow]=a1.y; As[sseg*8+6][srow]=a1.z; As[sseg*8+7][srow]=a1.w;
        Bs[skB][srB] = b0.x; Bs[skB+1][srB] = b0.y;
        __syncthreads();
        #pragma unroll
        for (int kk = 0; kk < 32; ++kk) {
            float4 a4 = *(const float4*)&As[kk][ty * 4];
            float b = Bs[kk][tx];
            acc[0] += a4.x * b; acc[1] += a4.y * b;
            acc[2] += a4.z * b; acc[3] += a4.w * b;
        }
    }
    #pragma unroll
    for (int i = 0; i < 4; ++i)
        k_cmp[(m0 + ty * 4 + i) * KVD + n0 + tx] = acc[i];
}

// ---------------------------------------------------------------------------
// Block summaries. grid (63,4,2). Padded 516-float segments (conflict-free).
// ---------------------------------------------------------------------------
__global__ __launch_bounds__(256) void nsa_summarize(
    const float* __restrict__ k_cmp, const float* __restrict__ v_cmp,
    const float* __restrict__ block_pos,
    const float* __restrict__ ck1_w, const float* __restrict__ ck1_b,
    const float* __restrict__ ck2_w, const float* __restrict__ ck2_b,
    const float* __restrict__ cv1_w, const float* __restrict__ cv1_b,
    const float* __restrict__ cv2_w, const float* __restrict__ cv2_b,
    float* __restrict__ ksum, float* __restrict__ vsum)
{
    const int n = blockIdx.x, k = blockIdx.y, which = blockIdx.z;
    const float* src = which ? v_cmp : k_cmp;
    const float* w1  = which ? cv1_w : ck1_w;
    const float* b1  = which ? cv1_b : ck1_b;
    const float* w2  = which ? cv2_w : ck2_w;
    const float* b2  = which ? cv2_b : ck2_b;
    float* dst       = which ? vsum  : ksum;

    __shared__ float flat[4 * 516];
    __shared__ float hidden[DH];
    const int tid = threadIdx.x;
    const int start = n * 16;

    for (int e = tid; e < 512; e += 256) {
        int p = e >> 4, d4 = e & 15;
        float4 s = *(const float4*)(src + ((start + p) * NKV + k) * DH + d4 * 4);
        float4 bp = *(const float4*)(block_pos + p * DH + d4 * 4);
        float4 r; r.x = s.x + bp.x; r.y = s.y + bp.y; r.z = s.z + bp.z; r.w = s.w + bp.w;
        *(float4*)&flat[(p >> 3) * 516 + (p & 7) * 64 + d4 * 4] = r;
    }
    __syncthreads();
    {
        int h = tid >> 2, part = tid & 3;
        const float* wr = w1 + h * 2048 + part * 512;
        const float* fl = flat + part * 516;
        float s = 0.0f;
        for (int j = 0; j < 512; j += 4) {
            float4 a = *(const float4*)(fl + j);
            float4 b = *(const float4*)(wr + j);
            s += a.x * b.x + a.y * b.y + a.z * b.z + a.w * b.w;
        }
        s += __shfl_xor(s, 1);
        s += __shfl_xor(s, 2);
        if (part == 0) hidden[h] = gelu_exact(s + b1[h]);
    }
    __syncthreads();
    {
        int dh = tid >> 2, part = tid & 3;
        const float* wr = w2 + dh * 64 + part * 16;
        float s = 0.0f;
        #pragma unroll
        for (int hh = 0; hh < 16; ++hh) s += hidden[part * 16 + hh] * wr[hh];
        s += __shfl_xor(s, 1);
        s += __shfl_xor(s, 2);
        if (part == 0) dst[(n * NKV + k) * DH + dh] = s + b2[dh];
    }
}

// ---------------------------------------------------------------------------
// Fused attention — EXACT round-5 body (measured: 230 us, VGPR 52, occ 42%,
// 0 bank conflicts). LDS broadcasts for q / softmax weights; bounded unrolls.
// Do NOT vectorize further (r2/r3) or replace broadcasts with __shfl (r7).
// ---------------------------------------------------------------------------
__global__ __launch_bounds__(256) void nsa_fused(
    const float* __restrict__ q,         // (16, T, 64)
    const float* __restrict__ gates_lin, // (T, 48)  pre-sigmoid
    const float* __restrict__ ksum,      // (63, 4, 64)
    const float* __restrict__ vsum,
    const float* __restrict__ k_slc,     // (T, 4, 64)
    const float* __restrict__ v_slc,
    const float* __restrict__ k_win,
    const float* __restrict__ v_win,
    float* __restrict__ out)             // (16, T, 64)
{
    const int t = blockIdx.x;
    const int k = blockIdx.y;
    const int tid = threadIdx.x;
    const int lane = tid & 63;
    const int r = tid >> 6;

    __shared__ float q_s[REP][DH];
    __shared__ float p_cmp_s[REP][64];
    __shared__ float sc_s[REP][256];
    __shared__ float chunk[64][DH + 2];   // +2: float2-aligned rows, even stride
    __shared__ int   sel_s[TOPN];

    // ---- load q ----
    q_s[r][lane] = q[((r * NKV + k) * T_LEN + t) * DH + lane];
    __syncthreads();

    // ---- compressed scores: lane = block index n ----
    float s = -1e30f;
    if (lane < NB) {
        bool vis = (lane * 16 + 31) <= t;
        if (vis) {
            float acc = 0.0f;
            const float* kr = ksum + (lane * NKV + k) * DH;
            #pragma unroll 16
            for (int d = 0; d < DH; ++d) acc += q_s[r][d] * kr[d];
            s = acc * 0.125f;
        }
    }
    float m = s;
    for (int off = 32; off; off >>= 1) m = fmaxf(m, __shfl_xor(m, off));
    float e = (lane < NB) ? expf(s - m) : 0.0f;
    float sum = e;
    for (int off = 32; off; off >>= 1) sum += __shfl_xor(sum, off);
    float p = e / sum;
    p_cmp_s[r][lane] = (lane < NB) ? p : 0.0f;
    __syncthreads();

    // ---- out_cmp: lane = d ----
    float ocmp = 0.0f;
    if (t >= 31) {
        for (int n = 0; n < NB; ++n)
            ocmp += p_cmp_s[r][n] * vsum[(n * NKV + k) * DH + lane];
    }

    // ---- top-8 selection (wave 0), stable ties ----
    if (r == 0) {
        float imp = (lane < NB)
            ? (p_cmp_s[0][lane] + p_cmp_s[1][lane] + p_cmp_s[2][lane] + p_cmp_s[3][lane])
            : -1e30f;
        const int idx = lane;
        for (int it = 0; it < TOPN; ++it) {
            float v = imp; int i = idx;
            for (int off = 32; off; off >>= 1) {
                float ov = __shfl_xor(v, off);
                int   oi = __shfl_xor(i, off);
                if (ov > v || (ov == v && oi < i)) { v = ov; i = oi; }
            }
            if (lane == 0) sel_s[it] = i;
            if (lane == i) imp = -1e30f;
        }
    }
    __syncthreads();

    // ---- selected branch ----
    float oslc = 0.0f;
    for (int c = 0; c < 4; ++c) {
        __syncthreads();
        for (int e2 = tid; e2 < 64 * 32; e2 += 256) {
            int pidx = e2 >> 5, d2 = e2 & 31;
            int j = c * 64 + pidx;
            int pos = sel_s[j >> 5] * 16 + (j & 31);
            *(float2*)&chunk[pidx][d2 * 2] =
                *(const float2*)&k_slc[(pos * NKV + k) * DH + d2 * 2];
        }
        __syncthreads();
        int j = c * 64 + lane;
        int pos = sel_s[j >> 5] * 16 + (j & 31);
        float acc = 0.0f;
        #pragma unroll 8
        for (int d2 = 0; d2 < 32; ++d2) {
            float2 qd = *(const float2*)&q_s[r][d2 * 2];
            float2 cd = *(const float2*)&chunk[lane][d2 * 2];
            acc += qd.x * cd.x + qd.y * cd.y;
        }
        sc_s[r][j] = (pos <= t) ? acc * 0.125f : -1e30f;
    }
    __syncthreads();
    {
        float v0 = sc_s[r][lane], v1 = sc_s[r][64 + lane];
        float v2 = sc_s[r][128 + lane], v3 = sc_s[r][192 + lane];
        float mx = fmaxf(fmaxf(v0, v1), fmaxf(v2, v3));
        for (int off = 32; off; off >>= 1) mx = fmaxf(mx, __shfl_xor(mx, off));
        float e0 = expf(v0 - mx), e1 = expf(v1 - mx), e2 = expf(v2 - mx), e3 = expf(v3 - mx);
        float sm = e0 + e1 + e2 + e3;
        for (int off = 32; off; off >>= 1) sm += __shfl_xor(sm, off);
        float inv = 1.0f / sm;
        sc_s[r][lane] = e0 * inv; sc_s[r][64 + lane] = e1 * inv;
        sc_s[r][128 + lane] = e2 * inv; sc_s[r][192 + lane] = e3 * inv;
    }
    for (int c = 0; c < 4; ++c) {
        __syncthreads();
        for (int e2 = tid; e2 < 64 * 32; e2 += 256) {
            int pidx = e2 >> 5, d2 = e2 & 31;
            int j = c * 64 + pidx;
            int pos = sel_s[j >> 5] * 16 + (j & 31);
            *(float2*)&chunk[pidx][d2 * 2] =
                *(const float2*)&v_slc[(pos * NKV + k) * DH + d2 * 2];
        }
        __syncthreads();
        #pragma unroll 4
        for (int p0 = 0; p0 < 64; p0 += 2) {
            float2 sv = *(const float2*)&sc_s[r][c * 64 + p0];
            oslc += sv.x * chunk[p0][lane] + sv.y * chunk[p0 + 1][lane];
        }
    }

    // ---- sliding-window branch ----
    float owin = 0.0f;
    const int j0 = (t >= 255) ? (t - 255) : 0;
    const int W = t - j0 + 1;
    for (int c = 0; c < 4; ++c) {
        __syncthreads();
        for (int e2 = tid; e2 < 64 * 32; e2 += 256) {
            int pidx = e2 >> 5, d2 = e2 & 31;
            int pos = j0 + c * 64 + pidx;
            *(float2*)&chunk[pidx][d2 * 2] =
                *(const float2*)&k_win[(pos * NKV + k) * DH + d2 * 2];
        }
        __syncthreads();
        int jj = c * 64 + lane;
        float acc = 0.0f;
        #pragma unroll 8
        for (int d2 = 0; d2 < 32; ++d2) {
            float2 qd = *(const float2*)&q_s[r][d2 * 2];
            float2 cd = *(const float2*)&chunk[lane][d2 * 2];
            acc += qd.x * cd.x + qd.y * cd.y;
        }
        sc_s[r][jj] = (jj < W) ? acc * 0.125f : -1e30f;
    }
    __syncthreads();
    {
        float v0 = sc_s[r][lane], v1 = sc_s[r][64 + lane];
        float v2 = sc_s[r][128 + lane], v3 = sc_s[r][192 + lane];
        float mx = fmaxf(fmaxf(v0, v1), fmaxf(v2, v3));
        for (int off = 32; off; off >>= 1) mx = fmaxf(mx, __shfl_xor(mx, off));
        float e0 = expf(v0 - mx), e1 = expf(v1 - mx), e2 = expf(v2 - mx), e3 = expf(v3 - mx);
        float sm = e0 + e1 + e2 + e3;
        for (int off = 32; off; off >>= 1) sm += __shfl_xor(sm, off);
        float inv = 1.0f / sm;
        sc_s[r][lane] = e0 * inv; sc_s[r][64 + lane] = e1 * inv;
        sc_s[r][128 + lane] = e2 * inv; sc_s[r][192 + lane] = e3 * inv;
    }
    for (int c = 0; c < 4; ++c) {
        __syncthreads();
        for (int e2 = tid; e2 < 64 * 32; e2 += 256) {
            int pidx = e2 >> 5, d2 = e2 & 31;
            int pos = j0 + c * 64 + pidx;
            *(float2*)&chunk[pidx][d2 * 2] =
                *(const float2*)&v_win[(pos * NKV + k) * DH + d2 * 2];
        }
        __syncthreads();
        #pragma unroll 4
        for (int p0 = 0; p0 < 64; p0 += 2) {
            float2 sv = *(const float2*)&sc_s[r][c * 64 + p0];
            owin += sv.x * chunk[p0][lane] + sv.y * chunk[p0 + 1][lane];
        }
    }

    // ---- gating + write (lane = d) ----
    const int hq = r * NKV + k;
    const float* gl = gates_lin + t * 48 + hq * 3;
    float g0 = sigmoidf(gl[0]);
    float g1 = sigmoidf(gl[1]);
    float g2 = sigmoidf(gl[2]);
    out[(hq * T_LEN + t) * DH + lane] = g0 * ocmp + g1 * oslc + g2 * owin;
}

extern "C" void kernel_launch(void* const* d_in, const int* in_sizes, int n_in,
                              void* d_out, int out_size, void* d_ws, size_t ws_size,
                              hipStream_t stream) {
    const float* x         = (const float*)d_in[0];
    const float* q         = (const float*)d_in[1];
    const float* gate_w    = (const float*)d_in[2];
    const float* gate_b    = (const float*)d_in[3];
    const float* wk_cmp    = (const float*)d_in[4];
    const float* wv_cmp    = (const float*)d_in[5];
    const float* wk_slc    = (const float*)d_in[6];
    const float* wv_slc    = (const float*)d_in[7];
    const float* wk_win    = (const float*)d_in[8];
    const float* wv_win    = (const float*)d_in[9];
    const float* block_pos = (const float*)d_in[10];
    const float* ck1_w     = (const float*)d_in[11];
    const float* ck1_b     = (const float*)d_in[12];
    const float* ck2_w     = (const float*)d_in[13];
    const float* ck2_b     = (const float*)d_in[14];
    const float* cv1_w     = (const float*)d_in[15];
    const float* cv1_b     = (const float*)d_in[16];
    const float* cv2_w     = (const float*)d_in[17];
    const float* cv2_b     = (const float*)d_in[18];
    float* out = (float*)d_out;

    float* ws = (float*)d_ws;
    float* gates_lin = ws;                         // 1024*48
    float* k_cmp = gates_lin + T_LEN * 48;         // 1024*256 each
    float* v_cmp = k_cmp + T_LEN * KVD;
    float* k_slc = v_cmp + T_LEN * KVD;
    float* v_slc = k_slc + T_LEN * KVD;
    float* k_win = v_slc + T_LEN * KVD;
    float* v_win = k_win + T_LEN * KVD;
    float* ksum  = v_win + T_LEN * KVD;            // 63*4*64 each
    float* vsum  = ksum + NB * KVD;

    dim3 blk(256);
    proj_gemm<<<dim3(21, 16), blk, 0, stream>>>(
        x, gate_w, gate_b, wv_cmp, wk_slc, wv_slc, wk_win, wv_win,
        gates_lin, v_cmp, k_slc, v_slc, k_win, v_win);
    gemm_kcmp_f32<<<dim3(16, 16), blk, 0, stream>>>(x, wk_cmp, k_cmp);
    nsa_summarize<<<dim3(NB, NKV, 2), blk, 0, stream>>>(
        k_cmp, v_cmp, block_pos,
        ck1_w, ck1_b, ck2_w, ck2_b, cv1_w, cv1_b, cv2_w, cv2_b,
        ksum, vsum);
    nsa_fused<<<dim3(T_LEN, NKV), blk, 0, stream>>>(
        q, gates_lin, ksum, vsum, k_slc, v_slc, k_win, v_win, out);
}

// Round 9
// 377.674 us; speedup vs baseline: 11.4258x; 1.0259x over previous
//
#include <hip/hip_runtime.h>
#include <hip/hip_bf16.h>
#include <math.h>

#define T_LEN 1024
#define D_MODEL 1024
#define NKV 4
#define REP 4
#define DH 64
#define NB 63
#define TOPN 8
#define KVD 256        // NKV*DH
#define LDIM2 1328     // virtual concatenated width without k_cmp

typedef __attribute__((ext_vector_type(8))) short bf16x8;
typedef __attribute__((ext_vector_type(4))) float f32x4;

__device__ __forceinline__ float gelu_exact(float x) {
    return 0.5f * x * (1.0f + erff(x * 0.70710678118654752f));
}
__device__ __forceinline__ float sigmoidf(float x) {
    return 1.0f / (1.0f + expf(-x));
}
// pack 8 f32 -> 8 bf16 via HW v_cvt_pk_bf16_f32 (RNE)
__device__ __forceinline__ bf16x8 cvt8(float4 a0, float4 a1) {
    union { __hip_bfloat162 v; short2 s; } u0, u1, u2, u3;
    u0.v = __float22bfloat162_rn(make_float2(a0.x, a0.y));
    u1.v = __float22bfloat162_rn(make_float2(a0.z, a0.w));
    u2.v = __float22bfloat162_rn(make_float2(a1.x, a1.y));
    u3.v = __float22bfloat162_rn(make_float2(a1.z, a1.w));
    bf16x8 r;
    r[0] = u0.s.x; r[1] = u0.s.y; r[2] = u1.s.x; r[3] = u1.s.y;
    r[4] = u2.s.x; r[5] = u2.s.y; r[6] = u3.s.x; r[7] = u3.s.y;
    return r;
}

// ---------------------------------------------------------------------------
// Merged projection dispatch, grid (25,16), dynamic LDS 17408 B:
//   bx <  21 : bf16 MFMA GEMM over virtual concat of 6 projections
//   bx >= 21 : f32 GEMM for k_cmp (selection-critical), 4 tiles of 64 cols
// The two paths are independent (disjoint outputs); merging overlaps them on
// the CU array instead of serializing two half-full dispatches.
// ---------------------------------------------------------------------------
__global__ __launch_bounds__(256) void proj_all(
    const float* __restrict__ x,
    const float* __restrict__ gate_w, const float* __restrict__ gate_b,
    const float* __restrict__ wk_cmp, const float* __restrict__ wv_cmp,
    const float* __restrict__ wk_slc, const float* __restrict__ wv_slc,
    const float* __restrict__ wk_win, const float* __restrict__ wv_win,
    float* __restrict__ gates_lin, float* __restrict__ k_cmp,
    float* __restrict__ v_cmp,
    float* __restrict__ k_slc, float* __restrict__ v_slc,
    float* __restrict__ k_win, float* __restrict__ v_win)
{
    extern __shared__ char smem[];
    const int tid = threadIdx.x;
    const int m0 = blockIdx.y * 64;

    if (blockIdx.x < 21) {
        // ---------------- bf16 MFMA path ----------------
        typedef unsigned short row40[40];
        row40* As = (row40*)smem;
        row40* Bs = (row40*)(smem + 64 * 40 * sizeof(unsigned short));
        const int lane = tid & 63;
        const int w = tid >> 6;
        const int n0 = blockIdx.x * 64;

        const int srow = tid >> 2;
        const int sseg = tid & 3;
        const float* ga = x + (m0 + srow) * D_MODEL + sseg * 8;
        const float* gb;
        {
            int nn = n0 + srow;
            if (nn < 48)        gb = gate_w + nn * D_MODEL;
            else if (nn < 304)  gb = wv_cmp + (nn - 48) * D_MODEL;
            else if (nn < 560)  gb = wk_slc + (nn - 304) * D_MODEL;
            else if (nn < 816)  gb = wv_slc + (nn - 560) * D_MODEL;
            else if (nn < 1072) gb = wk_win + (nn - 816) * D_MODEL;
            else if (nn < 1328) gb = wv_win + (nn - 1072) * D_MODEL;
            else                gb = gate_w;   // dummy, masked at store
            gb += sseg * 8;
        }

        f32x4 acc[4] = {};
        const int arow = (w << 4) + (lane & 15);
        const int kk8  = (lane >> 4) * 8;

        for (int k0 = 0; k0 < D_MODEL; k0 += 32) {
            float4 a0 = *(const float4*)(ga + k0);
            float4 a1 = *(const float4*)(ga + k0 + 4);
            float4 b0 = *(const float4*)(gb + k0);
            float4 b1 = *(const float4*)(gb + k0 + 4);
            bf16x8 ap = cvt8(a0, a1);
            bf16x8 bp = cvt8(b0, b1);
            __syncthreads();
            *(bf16x8*)&As[srow][sseg * 8] = ap;
            *(bf16x8*)&Bs[srow][sseg * 8] = bp;
            __syncthreads();
            bf16x8 af = *(bf16x8*)&As[arow][kk8];
            #pragma unroll
            for (int j = 0; j < 4; ++j) {
                bf16x8 bfr = *(bf16x8*)&Bs[j * 16 + (lane & 15)][kk8];
                acc[j] = __builtin_amdgcn_mfma_f32_16x16x32_bf16(af, bfr, acc[j], 0, 0, 0);
            }
        }

        // C/D layout: col = lane&15, row = (lane>>4)*4 + reg  [m89-verified]
        #pragma unroll
        for (int j = 0; j < 4; ++j) {
            int col = n0 + j * 16 + (lane & 15);
            if (col >= LDIM2) continue;
            int rbase = m0 + (w << 4) + (lane >> 4) * 4;
            float* dst; int cc; int stride = 256; float badd = 0.0f;
            if (col < 48)        { dst = gates_lin; cc = col;        stride = 48; badd = gate_b[col]; }
            else if (col < 304)  { dst = v_cmp;     cc = col - 48;   }
            else if (col < 560)  { dst = k_slc;     cc = col - 304;  }
            else if (col < 816)  { dst = v_slc;     cc = col - 560;  }
            else if (col < 1072) { dst = k_win;     cc = col - 816;  }
            else                 { dst = v_win;     cc = col - 1072; }
            #pragma unroll
            for (int rg = 0; rg < 4; ++rg)
                dst[(rbase + rg) * stride + cc] = acc[j][rg] + badd;
        }
    } else {
        // ---------------- f32 k_cmp path (r4-proven 64x64 tile) ----------------
        typedef float row68[68];
        row68* As = (row68*)smem;
        row68* Bs = (row68*)(smem + 32 * 68 * sizeof(float));
        const int tx = tid & 15, ty = tid >> 4;
        const int n0 = (blockIdx.x - 21) * 64;
        const int srow = tid >> 2, sseg = tid & 3;
        const float* ga = x + (m0 + srow) * D_MODEL + sseg * 8;
        const float* gb = wk_cmp + (n0 + srow) * D_MODEL + sseg * 8;

        float acc[4][4] = {};
        for (int k0 = 0; k0 < D_MODEL; k0 += 32) {
            float4 a0 = *(const float4*)(ga + k0);
            float4 a1 = *(const float4*)(ga + k0 + 4);
            float4 b0 = *(const float4*)(gb + k0);
            float4 b1 = *(const float4*)(gb + k0 + 4);
            __syncthreads();
            As[sseg*8+0][srow]=a0.x; As[sseg*8+1][srow]=a0.y; As[sseg*8+2][srow]=a0.z; As[sseg*8+3][srow]=a0.w;
            As[sseg*8+4][srow]=a1.x; As[sseg*8+5][srow]=a1.y; As[sseg*8+6][srow]=a1.z; As[sseg*8+7][srow]=a1.w;
            Bs[sseg*8+0][srow]=b0.x; Bs[sseg*8+1][srow]=b0.y; Bs[sseg*8+2][srow]=b0.z; Bs[sseg*8+3][srow]=b0.w;
            Bs[sseg*8+4][srow]=b1.x; Bs[sseg*8+5][srow]=b1.y; Bs[sseg*8+6][srow]=b1.z; Bs[sseg*8+7][srow]=b1.w;
            __syncthreads();
            #pragma unroll
            for (int kk = 0; kk < 32; ++kk) {
                float4 a4 = *(const float4*)&As[kk][ty * 4];
                float4 b4 = *(const float4*)&Bs[kk][tx * 4];
                acc[0][0] += a4.x*b4.x; acc[0][1] += a4.x*b4.y; acc[0][2] += a4.x*b4.z; acc[0][3] += a4.x*b4.w;
                acc[1][0] += a4.y*b4.x; acc[1][1] += a4.y*b4.y; acc[1][2] += a4.y*b4.z; acc[1][3] += a4.y*b4.w;
                acc[2][0] += a4.z*b4.x; acc[2][1] += a4.z*b4.y; acc[2][2] += a4.z*b4.z; acc[2][3] += a4.z*b4.w;
                acc[3][0] += a4.w*b4.x; acc[3][1] += a4.w*b4.y; acc[3][2] += a4.w*b4.z; acc[3][3] += a4.w*b4.w;
            }
        }
        #pragma unroll
        for (int i = 0; i < 4; ++i) {
            int mm = m0 + ty * 4 + i;
            #pragma unroll
            for (int j = 0; j < 4; ++j)
                k_cmp[mm * KVD + n0 + tx * 4 + j] = acc[i][j];
        }
    }
}

// ---------------------------------------------------------------------------
// Block summaries. grid (63,4,2). Padded 516-float segments (conflict-free).
// ---------------------------------------------------------------------------
__global__ __launch_bounds__(256) void nsa_summarize(
    const float* __restrict__ k_cmp, const float* __restrict__ v_cmp,
    const float* __restrict__ block_pos,
    const float* __restrict__ ck1_w, const float* __restrict__ ck1_b,
    const float* __restrict__ ck2_w, const float* __restrict__ ck2_b,
    const float* __restrict__ cv1_w, const float* __restrict__ cv1_b,
    const float* __restrict__ cv2_w, const float* __restrict__ cv2_b,
    float* __restrict__ ksum, float* __restrict__ vsum)
{
    const int n = blockIdx.x, k = blockIdx.y, which = blockIdx.z;
    const float* src = which ? v_cmp : k_cmp;
    const float* w1  = which ? cv1_w : ck1_w;
    const float* b1  = which ? cv1_b : ck1_b;
    const float* w2  = which ? cv2_w : ck2_w;
    const float* b2  = which ? cv2_b : ck2_b;
    float* dst       = which ? vsum  : ksum;

    __shared__ float flat[4 * 516];
    __shared__ float hidden[DH];
    const int tid = threadIdx.x;
    const int start = n * 16;

    for (int e = tid; e < 512; e += 256) {
        int p = e >> 4, d4 = e & 15;
        float4 s = *(const float4*)(src + ((start + p) * NKV + k) * DH + d4 * 4);
        float4 bp = *(const float4*)(block_pos + p * DH + d4 * 4);
        float4 r; r.x = s.x + bp.x; r.y = s.y + bp.y; r.z = s.z + bp.z; r.w = s.w + bp.w;
        *(float4*)&flat[(p >> 3) * 516 + (p & 7) * 64 + d4 * 4] = r;
    }
    __syncthreads();
    {
        int h = tid >> 2, part = tid & 3;
        const float* wr = w1 + h * 2048 + part * 512;
        const float* fl = flat + part * 516;
        float s = 0.0f;
        for (int j = 0; j < 512; j += 4) {
            float4 a = *(const float4*)(fl + j);
            float4 b = *(const float4*)(wr + j);
            s += a.x * b.x + a.y * b.y + a.z * b.z + a.w * b.w;
        }
        s += __shfl_xor(s, 1);
        s += __shfl_xor(s, 2);
        if (part == 0) hidden[h] = gelu_exact(s + b1[h]);
    }
    __syncthreads();
    {
        int dh = tid >> 2, part = tid & 3;
        const float* wr = w2 + dh * 64 + part * 16;
        float s = 0.0f;
        #pragma unroll
        for (int hh = 0; hh < 16; ++hh) s += hidden[part * 16 + hh] * wr[hh];
        s += __shfl_xor(s, 1);
        s += __shfl_xor(s, 2);
        if (part == 0) dst[(n * NKV + k) * DH + dh] = s + b2[dh];
    }
}

// ---------------------------------------------------------------------------
// Fused attention — round-5 body (measured: ~229 us, VGPR 52, 0 conflicts).
// LDS broadcasts for q / softmax weights; bounded unrolls. Do NOT fully
// vectorize (r2/r3 spill) or replace broadcasts with __shfl (r7 spill).
// ---------------------------------------------------------------------------
__global__ __launch_bounds__(256) void nsa_fused(
    const float* __restrict__ q,         // (16, T, 64)
    const float* __restrict__ gates_lin, // (T, 48)  pre-sigmoid
    const float* __restrict__ ksum,      // (63, 4, 64)
    const float* __restrict__ vsum,
    const float* __restrict__ k_slc,     // (T, 4, 64)
    const float* __restrict__ v_slc,
    const float* __restrict__ k_win,
    const float* __restrict__ v_win,
    float* __restrict__ out)             // (16, T, 64)
{
    const int t = blockIdx.x;
    const int k = blockIdx.y;
    const int tid = threadIdx.x;
    const int lane = tid & 63;
    const int r = tid >> 6;

    __shared__ float q_s[REP][DH];
    __shared__ float p_cmp_s[REP][64];
    __shared__ float sc_s[REP][256];
    __shared__ float chunk[64][DH + 2];
    __shared__ int   sel_s[TOPN];

    // ---- load q ----
    q_s[r][lane] = q[((r * NKV + k) * T_LEN + t) * DH + lane];
    __syncthreads();

    // ---- compressed scores: lane = block index n ----
    float s = -1e30f;
    if (lane < NB) {
        bool vis = (lane * 16 + 31) <= t;
        if (vis) {
            float acc = 0.0f;
            const float* kr = ksum + (lane * NKV + k) * DH;
            #pragma unroll 16
            for (int d = 0; d < DH; ++d) acc += q_s[r][d] * kr[d];
            s = acc * 0.125f;
        }
    }
    float m = s;
    for (int off = 32; off; off >>= 1) m = fmaxf(m, __shfl_xor(m, off));
    float e = (lane < NB) ? expf(s - m) : 0.0f;
    float sum = e;
    for (int off = 32; off; off >>= 1) sum += __shfl_xor(sum, off);
    float p = e / sum;
    p_cmp_s[r][lane] = (lane < NB) ? p : 0.0f;
    __syncthreads();

    // ---- out_cmp: lane = d ----
    float ocmp = 0.0f;
    if (t >= 31) {
        for (int n = 0; n < NB; ++n)
            ocmp += p_cmp_s[r][n] * vsum[(n * NKV + k) * DH + lane];
    }

    // ---- top-8 selection (wave 0), stable ties ----
    if (r == 0) {
        float imp = (lane < NB)
            ? (p_cmp_s[0][lane] + p_cmp_s[1][lane] + p_cmp_s[2][lane] + p_cmp_s[3][lane])
            : -1e30f;
        const int idx = lane;
        for (int it = 0; it < TOPN; ++it) {
            float v = imp; int i = idx;
            for (int off = 32; off; off >>= 1) {
                float ov = __shfl_xor(v, off);
                int   oi = __shfl_xor(i, off);
                if (ov > v || (ov == v && oi < i)) { v = ov; i = oi; }
            }
            if (lane == 0) sel_s[it] = i;
            if (lane == i) imp = -1e30f;
        }
    }
    __syncthreads();

    // ---- selected branch ----
    float oslc = 0.0f;
    for (int c = 0; c < 4; ++c) {
        __syncthreads();
        for (int e2 = tid; e2 < 64 * 32; e2 += 256) {
            int pidx = e2 >> 5, d2 = e2 & 31;
            int j = c * 64 + pidx;
            int pos = sel_s[j >> 5] * 16 + (j & 31);
            *(float2*)&chunk[pidx][d2 * 2] =
                *(const float2*)&k_slc[(pos * NKV + k) * DH + d2 * 2];
        }
        __syncthreads();
        int j = c * 64 + lane;
        int pos = sel_s[j >> 5] * 16 + (j & 31);
        float acc = 0.0f;
        #pragma unroll 8
        for (int d2 = 0; d2 < 32; ++d2) {
            float2 qd = *(const float2*)&q_s[r][d2 * 2];
            float2 cd = *(const float2*)&chunk[lane][d2 * 2];
            acc += qd.x * cd.x + qd.y * cd.y;
        }
        sc_s[r][j] = (pos <= t) ? acc * 0.125f : -1e30f;
    }
    __syncthreads();
    {
        float v0 = sc_s[r][lane], v1 = sc_s[r][64 + lane];
        float v2 = sc_s[r][128 + lane], v3 = sc_s[r][192 + lane];
        float mx = fmaxf(fmaxf(v0, v1), fmaxf(v2, v3));
        for (int off = 32; off; off >>= 1) mx = fmaxf(mx, __shfl_xor(mx, off));
        float e0 = expf(v0 - mx), e1 = expf(v1 - mx), e2 = expf(v2 - mx), e3 = expf(v3 - mx);
        float sm = e0 + e1 + e2 + e3;
        for (int off = 32; off; off >>= 1) sm += __shfl_xor(sm, off);
        float inv = 1.0f / sm;
        sc_s[r][lane] = e0 * inv; sc_s[r][64 + lane] = e1 * inv;
        sc_s[r][128 + lane] = e2 * inv; sc_s[r][192 + lane] = e3 * inv;
    }
    for (int c = 0; c < 4; ++c) {
        __syncthreads();
        for (int e2 = tid; e2 < 64 * 32; e2 += 256) {
            int pidx = e2 >> 5, d2 = e2 & 31;
            int j = c * 64 + pidx;
            int pos = sel_s[j >> 5] * 16 + (j & 31);
            *(float2*)&chunk[pidx][d2 * 2] =
                *(const float2*)&v_slc[(pos * NKV + k) * DH + d2 * 2];
        }
        __syncthreads();
        #pragma unroll 4
        for (int p0 = 0; p0 < 64; p0 += 2) {
            float2 sv = *(const float2*)&sc_s[r][c * 64 + p0];
            oslc += sv.x * chunk[p0][lane] + sv.y * chunk[p0 + 1][lane];
        }
    }

    // ---- sliding-window branch ----
    float owin = 0.0f;
    const int j0 = (t >= 255) ? (t - 255) : 0;
    const int W = t - j0 + 1;
    for (int c = 0; c < 4; ++c) {
        __syncthreads();
        for (int e2 = tid; e2 < 64 * 32; e2 += 256) {
            int pidx = e2 >> 5, d2 = e2 & 31;
            int pos = j0 + c * 64 + pidx;
            *(float2*)&chunk[pidx][d2 * 2] =
                *(const float2*)&k_win[(pos * NKV + k) * DH + d2 * 2];
        }
        __syncthreads();
        int jj = c * 64 + lane;
        float acc = 0.0f;
        #pragma unroll 8
        for (int d2 = 0; d2 < 32; ++d2) {
            float2 qd = *(const float2*)&q_s[r][d2 * 2];
            float2 cd = *(const float2*)&chunk[lane][d2 * 2];
            acc += qd.x * cd.x + qd.y * cd.y;
        }
        sc_s[r][jj] = (jj < W) ? acc * 0.125f : -1e30f;
    }
    __syncthreads();
    {
        float v0 = sc_s[r][lane], v1 = sc_s[r][64 + lane];
        float v2 = sc_s[r][128 + lane], v3 = sc_s[r][192 + lane];
        float mx = fmaxf(fmaxf(v0, v1), fmaxf(v2, v3));
        for (int off = 32; off; off >>= 1) mx = fmaxf(mx, __shfl_xor(mx, off));
        float e0 = expf(v0 - mx), e1 = expf(v1 - mx), e2 = expf(v2 - mx), e3 = expf(v3 - mx);
        float sm = e0 + e1 + e2 + e3;
        for (int off = 32; off; off >>= 1) sm += __shfl_xor(sm, off);
        float inv = 1.0f / sm;
        sc_s[r][lane] = e0 * inv; sc_s[r][64 + lane] = e1 * inv;
        sc_s[r][128 + lane] = e2 * inv; sc_s[r][192 + lane] = e3 * inv;
    }
    for (int c = 0; c < 4; ++c) {
        __syncthreads();
        for (int e2 = tid; e2 < 64 * 32; e2 += 256) {
            int pidx = e2 >> 5, d2 = e2 & 31;
            int pos = j0 + c * 64 + pidx;
            *(float2*)&chunk[pidx][d2 * 2] =
                *(const float2*)&v_win[(pos * NKV + k) * DH + d2 * 2];
        }
        __syncthreads();
        #pragma unroll 4
        for (int p0 = 0; p0 < 64; p0 += 2) {
            float2 sv = *(const float2*)&sc_s[r][c * 64 + p0];
            owin += sv.x * chunk[p0][lane] + sv.y * chunk[p0 + 1][lane];
        }
    }

    // ---- gating + write (lane = d) ----
    const int hq = r * NKV + k;
    const float* gl = gates_lin + t * 48 + hq * 3;
    float g0 = sigmoidf(gl[0]);
    float g1 = sigmoidf(gl[1]);
    float g2 = sigmoidf(gl[2]);
    out[(hq * T_LEN + t) * DH + lane] = g0 * ocmp + g1 * oslc + g2 * owin;
}

extern "C" void kernel_launch(void* const* d_in, const int* in_sizes, int n_in,
                              void* d_out, int out_size, void* d_ws, size_t ws_size,
                              hipStream_t stream) {
    const float* x         = (const float*)d_in[0];
    const float* q         = (const float*)d_in[1];
    const float* gate_w    = (const float*)d_in[2];
    const float* gate_b    = (const float*)d_in[3];
    const float* wk_cmp    = (const float*)d_in[4];
    const float* wv_cmp    = (const float*)d_in[5];
    const float* wk_slc    = (const float*)d_in[6];
    const float* wv_slc    = (const float*)d_in[7];
    const float* wk_win    = (const float*)d_in[8];
    const float* wv_win    = (const float*)d_in[9];
    const float* block_pos = (const float*)d_in[10];
    const float* ck1_w     = (const float*)d_in[11];
    const float* ck1_b     = (const float*)d_in[12];
    const float* ck2_w     = (const float*)d_in[13];
    const float* ck2_b     = (const float*)d_in[14];
    const float* cv1_w     = (const float*)d_in[15];
    const float* cv1_b     = (const float*)d_in[16];
    const float* cv2_w     = (const float*)d_in[17];
    const float* cv2_b     = (const float*)d_in[18];
    float* out = (float*)d_out;

    float* ws = (float*)d_ws;
    float* gates_lin = ws;                         // 1024*48
    float* k_cmp = gates_lin + T_LEN * 48;         // 1024*256 each
    float* v_cmp = k_cmp + T_LEN * KVD;
    float* k_slc = v_cmp + T_LEN * KVD;
    float* v_slc = k_slc + T_LEN * KVD;
    float* k_win = v_slc + T_LEN * KVD;
    float* v_win = k_win + T_LEN * KVD;
    float* ksum  = v_win + T_LEN * KVD;            // 63*4*64 each
    float* vsum  = ksum + NB * KVD;

    dim3 blk(256);
    // merged: 6 bf16-MFMA projections + f32 k_cmp, one dispatch, overlapped
    size_t smem_bytes = 2 * 32 * 68 * sizeof(float);   // 17408 >= bf16 path's 10240
    proj_all<<<dim3(25, 16), blk, smem_bytes, stream>>>(
        x, gate_w, gate_b, wk_cmp, wv_cmp, wk_slc, wv_slc, wk_win, wv_win,
        gates_lin, k_cmp, v_cmp, k_slc, v_slc, k_win, v_win);
    nsa_summarize<<<dim3(NB, NKV, 2), blk, 0, stream>>>(
        k_cmp, v_cmp, block_pos,
        ck1_w, ck1_b, ck2_w, ck2_b, cv1_w, cv1_b, cv2_w, cv2_b,
        ksum, vsum);
    nsa_fused<<<dim3(T_LEN, NKV), blk, 0, stream>>>(
        q, gates_lin, ksum, vsum, k_slc, v_slc, k_win, v_win, out);
}

// Round 10
// 288.964 us; speedup vs baseline: 14.9334x; 1.3070x over previous
//
#include <hip/hip_runtime.h>
#include <hip/hip_bf16.h>
#include <math.h>

#define T_LEN 1024
#define D_MODEL 1024
#define NKV 4
#define REP 4
#define DH 64
#define NB 63
#define TOPN 8
#define KVD 256        // NKV*DH
#define LDIM2 1328     // virtual concatenated width without k_cmp
#define TQ 16          // query tile for flash kernel

typedef __attribute__((ext_vector_type(8))) short bf16x8;
typedef __attribute__((ext_vector_type(4))) float f32x4;

__device__ __forceinline__ float gelu_exact(float x) {
    return 0.5f * x * (1.0f + erff(x * 0.70710678118654752f));
}
__device__ __forceinline__ float sigmoidf(float x) {
    return 1.0f / (1.0f + expf(-x));
}
// pack 8 f32 -> 8 bf16 via HW v_cvt_pk_bf16_f32 (RNE)
__device__ __forceinline__ bf16x8 cvt8(float4 a0, float4 a1) {
    union { __hip_bfloat162 v; short2 s; } u0, u1, u2, u3;
    u0.v = __float22bfloat162_rn(make_float2(a0.x, a0.y));
    u1.v = __float22bfloat162_rn(make_float2(a0.z, a0.w));
    u2.v = __float22bfloat162_rn(make_float2(a1.x, a1.y));
    u3.v = __float22bfloat162_rn(make_float2(a1.z, a1.w));
    bf16x8 r;
    r[0] = u0.s.x; r[1] = u0.s.y; r[2] = u1.s.x; r[3] = u1.s.y;
    r[4] = u2.s.x; r[5] = u2.s.y; r[6] = u3.s.x; r[7] = u3.s.y;
    return r;
}

// ---------------------------------------------------------------------------
// Merged projection dispatch, grid (25,16), dynamic LDS 17408 B (unchanged).
// ---------------------------------------------------------------------------
__global__ __launch_bounds__(256) void proj_all(
    const float* __restrict__ x,
    const float* __restrict__ gate_w, const float* __restrict__ gate_b,
    const float* __restrict__ wk_cmp, const float* __restrict__ wv_cmp,
    const float* __restrict__ wk_slc, const float* __restrict__ wv_slc,
    const float* __restrict__ wk_win, const float* __restrict__ wv_win,
    float* __restrict__ gates_lin, float* __restrict__ k_cmp,
    float* __restrict__ v_cmp,
    float* __restrict__ k_slc, float* __restrict__ v_slc,
    float* __restrict__ k_win, float* __restrict__ v_win)
{
    extern __shared__ char smem[];
    const int tid = threadIdx.x;
    const int m0 = blockIdx.y * 64;

    if (blockIdx.x < 21) {
        typedef unsigned short row40[40];
        row40* As = (row40*)smem;
        row40* Bs = (row40*)(smem + 64 * 40 * sizeof(unsigned short));
        const int lane = tid & 63;
        const int w = tid >> 6;
        const int n0 = blockIdx.x * 64;

        const int srow = tid >> 2;
        const int sseg = tid & 3;
        const float* ga = x + (m0 + srow) * D_MODEL + sseg * 8;
        const float* gb;
        {
            int nn = n0 + srow;
            if (nn < 48)        gb = gate_w + nn * D_MODEL;
            else if (nn < 304)  gb = wv_cmp + (nn - 48) * D_MODEL;
            else if (nn < 560)  gb = wk_slc + (nn - 304) * D_MODEL;
            else if (nn < 816)  gb = wv_slc + (nn - 560) * D_MODEL;
            else if (nn < 1072) gb = wk_win + (nn - 816) * D_MODEL;
            else if (nn < 1328) gb = wv_win + (nn - 1072) * D_MODEL;
            else                gb = gate_w;
            gb += sseg * 8;
        }

        f32x4 acc[4] = {};
        const int arow = (w << 4) + (lane & 15);
        const int kk8  = (lane >> 4) * 8;

        for (int k0 = 0; k0 < D_MODEL; k0 += 32) {
            float4 a0 = *(const float4*)(ga + k0);
            float4 a1 = *(const float4*)(ga + k0 + 4);
            float4 b0 = *(const float4*)(gb + k0);
            float4 b1 = *(const float4*)(gb + k0 + 4);
            bf16x8 ap = cvt8(a0, a1);
            bf16x8 bp = cvt8(b0, b1);
            __syncthreads();
            *(bf16x8*)&As[srow][sseg * 8] = ap;
            *(bf16x8*)&Bs[srow][sseg * 8] = bp;
            __syncthreads();
            bf16x8 af = *(bf16x8*)&As[arow][kk8];
            #pragma unroll
            for (int j = 0; j < 4; ++j) {
                bf16x8 bfr = *(bf16x8*)&Bs[j * 16 + (lane & 15)][kk8];
                acc[j] = __builtin_amdgcn_mfma_f32_16x16x32_bf16(af, bfr, acc[j], 0, 0, 0);
            }
        }

        #pragma unroll
        for (int j = 0; j < 4; ++j) {
            int col = n0 + j * 16 + (lane & 15);
            if (col >= LDIM2) continue;
            int rbase = m0 + (w << 4) + (lane >> 4) * 4;
            float* dst; int cc; int stride = 256; float badd = 0.0f;
            if (col < 48)        { dst = gates_lin; cc = col;        stride = 48; badd = gate_b[col]; }
            else if (col < 304)  { dst = v_cmp;     cc = col - 48;   }
            else if (col < 560)  { dst = k_slc;     cc = col - 304;  }
            else if (col < 816)  { dst = v_slc;     cc = col - 560;  }
            else if (col < 1072) { dst = k_win;     cc = col - 816;  }
            else                 { dst = v_win;     cc = col - 1072; }
            #pragma unroll
            for (int rg = 0; rg < 4; ++rg)
                dst[(rbase + rg) * stride + cc] = acc[j][rg] + badd;
        }
    } else {
        typedef float row68[68];
        row68* As = (row68*)smem;
        row68* Bs = (row68*)(smem + 32 * 68 * sizeof(float));
        const int tx = tid & 15, ty = tid >> 4;
        const int n0 = (blockIdx.x - 21) * 64;
        const int srow = tid >> 2, sseg = tid & 3;
        const float* ga = x + (m0 + srow) * D_MODEL + sseg * 8;
        const float* gb = wk_cmp + (n0 + srow) * D_MODEL + sseg * 8;

        float acc[4][4] = {};
        for (int k0 = 0; k0 < D_MODEL; k0 += 32) {
            float4 a0 = *(const float4*)(ga + k0);
            float4 a1 = *(const float4*)(ga + k0 + 4);
            float4 b0 = *(const float4*)(gb + k0);
            float4 b1 = *(const float4*)(gb + k0 + 4);
            __syncthreads();
            As[sseg*8+0][srow]=a0.x; As[sseg*8+1][srow]=a0.y; As[sseg*8+2][srow]=a0.z; As[sseg*8+3][srow]=a0.w;
            As[sseg*8+4][srow]=a1.x; As[sseg*8+5][srow]=a1.y; As[sseg*8+6][srow]=a1.z; As[sseg*8+7][srow]=a1.w;
            Bs[sseg*8+0][srow]=b0.x; Bs[sseg*8+1][srow]=b0.y; Bs[sseg*8+2][srow]=b0.z; Bs[sseg*8+3][srow]=b0.w;
            Bs[sseg*8+4][srow]=b1.x; Bs[sseg*8+5][srow]=b1.y; Bs[sseg*8+6][srow]=b1.z; Bs[sseg*8+7][srow]=b1.w;
            __syncthreads();
            #pragma unroll
            for (int kk = 0; kk < 32; ++kk) {
                float4 a4 = *(const float4*)&As[kk][ty * 4];
                float4 b4 = *(const float4*)&Bs[kk][tx * 4];
                acc[0][0] += a4.x*b4.x; acc[0][1] += a4.x*b4.y; acc[0][2] += a4.x*b4.z; acc[0][3] += a4.x*b4.w;
                acc[1][0] += a4.y*b4.x; acc[1][1] += a4.y*b4.y; acc[1][2] += a4.y*b4.z; acc[1][3] += a4.y*b4.w;
                acc[2][0] += a4.z*b4.x; acc[2][1] += a4.z*b4.y; acc[2][2] += a4.z*b4.z; acc[2][3] += a4.z*b4.w;
                acc[3][0] += a4.w*b4.x; acc[3][1] += a4.w*b4.y; acc[3][2] += a4.w*b4.z; acc[3][3] += a4.w*b4.w;
            }
        }
        #pragma unroll
        for (int i = 0; i < 4; ++i) {
            int mm = m0 + ty * 4 + i;
            #pragma unroll
            for (int j = 0; j < 4; ++j)
                k_cmp[mm * KVD + n0 + tx * 4 + j] = acc[i][j];
        }
    }
}

// ---------------------------------------------------------------------------
// Block summaries (unchanged). grid (63,4,2).
// ---------------------------------------------------------------------------
__global__ __launch_bounds__(256) void nsa_summarize(
    const float* __restrict__ k_cmp, const float* __restrict__ v_cmp,
    const float* __restrict__ block_pos,
    const float* __restrict__ ck1_w, const float* __restrict__ ck1_b,
    const float* __restrict__ ck2_w, const float* __restrict__ ck2_b,
    const float* __restrict__ cv1_w, const float* __restrict__ cv1_b,
    const float* __restrict__ cv2_w, const float* __restrict__ cv2_b,
    float* __restrict__ ksum, float* __restrict__ vsum)
{
    const int n = blockIdx.x, k = blockIdx.y, which = blockIdx.z;
    const float* src = which ? v_cmp : k_cmp;
    const float* w1  = which ? cv1_w : ck1_w;
    const float* b1  = which ? cv1_b : ck1_b;
    const float* w2  = which ? cv2_w : ck2_w;
    const float* b2  = which ? cv2_b : ck2_b;
    float* dst       = which ? vsum  : ksum;

    __shared__ float flat[4 * 516];
    __shared__ float hidden[DH];
    const int tid = threadIdx.x;
    const int start = n * 16;

    for (int e = tid; e < 512; e += 256) {
        int p = e >> 4, d4 = e & 15;
        float4 s = *(const float4*)(src + ((start + p) * NKV + k) * DH + d4 * 4);
        float4 bp = *(const float4*)(block_pos + p * DH + d4 * 4);
        float4 r; r.x = s.x + bp.x; r.y = s.y + bp.y; r.z = s.z + bp.z; r.w = s.w + bp.w;
        *(float4*)&flat[(p >> 3) * 516 + (p & 7) * 64 + d4 * 4] = r;
    }
    __syncthreads();
    {
        int h = tid >> 2, part = tid & 3;
        const float* wr = w1 + h * 2048 + part * 512;
        const float* fl = flat + part * 516;
        float s = 0.0f;
        for (int j = 0; j < 512; j += 4) {
            float4 a = *(const float4*)(fl + j);
            float4 b = *(const float4*)(wr + j);
            s += a.x * b.x + a.y * b.y + a.z * b.z + a.w * b.w;
        }
        s += __shfl_xor(s, 1);
        s += __shfl_xor(s, 2);
        if (part == 0) hidden[h] = gelu_exact(s + b1[h]);
    }
    __syncthreads();
    {
        int dh = tid >> 2, part = tid & 3;
        const float* wr = w2 + dh * 64 + part * 16;
        float s = 0.0f;
        #pragma unroll
        for (int hh = 0; hh < 16; ++hh) s += hidden[part * 16 + hh] * wr[hh];
        s += __shfl_xor(s, 1);
        s += __shfl_xor(s, 2);
        if (part == 0) dst[(n * NKV + k) * DH + dh] = s + b2[dh];
    }
}

// ---------------------------------------------------------------------------
// Compressed branch + top-8 selection (r5-proven f32 path, selection exact).
// Emits raw ocmp (ungated) and a 64-bit selected-block mask per (k,t).
// grid (1024, 4).
// ---------------------------------------------------------------------------
__global__ __launch_bounds__(256) void nsa_cmp(
    const float* __restrict__ q,
    const float* __restrict__ ksum, const float* __restrict__ vsum,
    float* __restrict__ ocmp_ws, unsigned int* __restrict__ selmask_ws)
{
    const int t = blockIdx.x, k = blockIdx.y;
    const int tid = threadIdx.x, lane = tid & 63, r = tid >> 6;

    __shared__ float q_s[REP][DH];
    __shared__ float p_cmp_s[REP][64];

    q_s[r][lane] = q[((r * NKV + k) * T_LEN + t) * DH + lane];
    __syncthreads();

    float s = -1e30f;
    if (lane < NB) {
        bool vis = (lane * 16 + 31) <= t;
        if (vis) {
            float acc = 0.0f;
            const float* kr = ksum + (lane * NKV + k) * DH;
            #pragma unroll 16
            for (int d = 0; d < DH; ++d) acc += q_s[r][d] * kr[d];
            s = acc * 0.125f;
        }
    }
    float m = s;
    for (int off = 32; off; off >>= 1) m = fmaxf(m, __shfl_xor(m, off));
    float e = (lane < NB) ? expf(s - m) : 0.0f;
    float sum = e;
    for (int off = 32; off; off >>= 1) sum += __shfl_xor(sum, off);
    float p = e / sum;
    p_cmp_s[r][lane] = (lane < NB) ? p : 0.0f;
    __syncthreads();

    // ocmp (raw, ungated): lane = d
    float ocmp = 0.0f;
    if (t >= 31) {
        for (int n = 0; n < NB; ++n)
            ocmp += p_cmp_s[r][n] * vsum[(n * NKV + k) * DH + lane];
    }

    // top-8 on wave 0, stable lowest-index ties; lane 0 builds the bitmask
    if (r == 0) {
        float imp = (lane < NB)
            ? (p_cmp_s[0][lane] + p_cmp_s[1][lane] + p_cmp_s[2][lane] + p_cmp_s[3][lane])
            : -1e30f;
        unsigned long long msk = 0ull;
        for (int it = 0; it < TOPN; ++it) {
            float v = imp; int i = lane;
            for (int off = 32; off; off >>= 1) {
                float ov = __shfl_xor(v, off);
                int   oi = __shfl_xor(i, off);
                if (ov > v || (ov == v && oi < i)) { v = ov; i = oi; }
            }
            msk |= 1ull << i;           // i is wave-uniform after the butterfly
            if (lane == i) imp = -1e30f;
        }
        if (lane == 0) {
            selmask_ws[(k * T_LEN + t) * 2 + 0] = (unsigned int)(msk & 0xffffffffu);
            selmask_ws[(k * T_LEN + t) * 2 + 1] = (unsigned int)(msk >> 32);
        }
    }

    const int hq = r * NKV + k;
    ocmp_ws[(hq * T_LEN + t) * DH + lane] = ocmp;
}

// ---------------------------------------------------------------------------
// Flash machinery for the selected / window branches.
// Equivalence (sel): position p belongs to selected block b iff b ∈ {p>>4,
// (p>>4)-1}; overlapping-block duplicates contribute with multiplicity, so
// weight = membership count ∈ {0,1,2}. Softmax(S-list) == weighted softmax
// over the position scan. Two-sweep (exact max, fixed-M) — no online rescale.
// ---------------------------------------------------------------------------
template<bool SEL>
__device__ __forceinline__ float weightf(int p, int tq, unsigned mk0, unsigned mk1) {
    if (SEL) {
        int b = p >> 4;
        unsigned c = (b < 32) ? ((mk0 >> b) & 1u) : ((mk1 >> (b - 32)) & 1u);
        int b2 = b - 1;
        if (b2 >= 0)
            c += (b2 < 32) ? ((mk0 >> b2) & 1u) : ((mk1 >> (b2 - 32)) & 1u);
        return (p <= tq) ? (float)c : 0.0f;
    } else {
        return (p <= tq && p > tq - 256) ? 1.0f : 0.0f;
    }
}

__device__ __forceinline__ void stage_k_bf16(const float* kptr, int k, int cb, int tid,
                                             unsigned short (*ks)[72]) {
    int row = tid >> 2, dseg = tid & 3;
    const float* src = kptr + (((cb << 6) + row) * NKV + k) * DH + dseg * 16;
    float4 a0 = *(const float4*)(src);
    float4 a1 = *(const float4*)(src + 4);
    float4 a2 = *(const float4*)(src + 8);
    float4 a3 = *(const float4*)(src + 12);
    *(bf16x8*)&ks[row][dseg * 16]     = cvt8(a0, a1);
    *(bf16x8*)&ks[row][dseg * 16 + 8] = cvt8(a2, a3);
}

__device__ __forceinline__ void stage_v_t(const float* vptr, int k, int cb, int tid,
                                          unsigned short (*vt)[88]) {
    int l = tid & 63, wv = tid >> 6;
    int dbase = wv * 16 + ((l >> 5) << 3);    // 8 dims per thread
    int pp = (l & 31) * 2;                    // position pair
    const float* v0 = vptr + (((cb << 6) + pp) * NKV + k) * DH + dbase;
    const float* v1 = v0 + NKV * DH;
    float4 x0 = *(const float4*)v0, x1 = *(const float4*)(v0 + 4);
    float4 y0 = *(const float4*)v1, y1 = *(const float4*)(v1 + 4);
    union { __hip_bfloat162 v; unsigned u; } t_;
    t_.v = __float22bfloat162_rn(make_float2(x0.x, y0.x)); *(unsigned*)&vt[dbase + 0][pp] = t_.u;
    t_.v = __float22bfloat162_rn(make_float2(x0.y, y0.y)); *(unsigned*)&vt[dbase + 1][pp] = t_.u;
    t_.v = __float22bfloat162_rn(make_float2(x0.z, y0.z)); *(unsigned*)&vt[dbase + 2][pp] = t_.u;
    t_.v = __float22bfloat162_rn(make_float2(x0.w, y0.w)); *(unsigned*)&vt[dbase + 3][pp] = t_.u;
    t_.v = __float22bfloat162_rn(make_float2(x1.x, y1.x)); *(unsigned*)&vt[dbase + 4][pp] = t_.u;
    t_.v = __float22bfloat162_rn(make_float2(x1.y, y1.y)); *(unsigned*)&vt[dbase + 5][pp] = t_.u;
    t_.v = __float22bfloat162_rn(make_float2(x1.z, y1.z)); *(unsigned*)&vt[dbase + 6][pp] = t_.u;
    t_.v = __float22bfloat162_rn(make_float2(x1.w, y1.w)); *(unsigned*)&vt[dbase + 7][pp] = t_.u;
}

template<bool SEL>
__device__ __forceinline__ void flash_branch(
    const float* kptr, const float* vptr, int k, int t0, int c0, int c1,
    int tid, int quad, int col,
    bf16x8 qf0, bf16x8 qf1,
    unsigned short (*ks)[72], unsigned short (*vt)[88], float (*ps)[76],
    const unsigned int (*selm)[2],
    f32x4 (&O)[4])
{
    unsigned mk0[4] = {0,0,0,0}, mk1[4] = {0,0,0,0};
    int tq[4];
    #pragma unroll
    for (int g = 0; g < 4; ++g) {
        int row = quad * 4 + g;
        tq[g] = t0 + row;
        if (SEL) { mk0[g] = selm[row][0]; mk1[g] = selm[row][1]; }
    }

    // ---- sweep 1: exact masked max per query row ----
    float M[4] = {-1e30f, -1e30f, -1e30f, -1e30f};
    for (int cb = c0; cb <= c1; ++cb) {
        __syncthreads();
        stage_k_bf16(kptr, k, cb, tid, ks);
        __syncthreads();
        #pragma unroll
        for (int nt = 0; nt < 4; ++nt) {
            bf16x8 b0 = *(const bf16x8*)&ks[nt * 16 + col][quad * 8];
            bf16x8 b1 = *(const bf16x8*)&ks[nt * 16 + col][32 + quad * 8];
            f32x4 sc = {0.f, 0.f, 0.f, 0.f};
            sc = __builtin_amdgcn_mfma_f32_16x16x32_bf16(qf0, b0, sc, 0, 0, 0);
            sc = __builtin_amdgcn_mfma_f32_16x16x32_bf16(qf1, b1, sc, 0, 0, 0);
            int p = (cb << 6) + nt * 16 + col;
            #pragma unroll
            for (int g = 0; g < 4; ++g) {
                float w = weightf<SEL>(p, tq[g], mk0[g], mk1[g]);
                float s = sc[g] * 0.125f;
                if (w > 0.0f) M[g] = fmaxf(M[g], s);
            }
        }
    }
    #pragma unroll
    for (int g = 0; g < 4; ++g) {
        M[g] = fmaxf(M[g], __shfl_xor(M[g], 1));
        M[g] = fmaxf(M[g], __shfl_xor(M[g], 2));
        M[g] = fmaxf(M[g], __shfl_xor(M[g], 4));
        M[g] = fmaxf(M[g], __shfl_xor(M[g], 8));
    }

    // ---- sweep 2: exp / l / P·V with fixed M ----
    float l[4] = {0.f, 0.f, 0.f, 0.f};
    f32x4 z = {0.f, 0.f, 0.f, 0.f};
    O[0] = z; O[1] = z; O[2] = z; O[3] = z;

    for (int cb = c0; cb <= c1; ++cb) {
        __syncthreads();
        stage_k_bf16(kptr, k, cb, tid, ks);
        stage_v_t(vptr, k, cb, tid, vt);
        __syncthreads();
        #pragma unroll
        for (int nt = 0; nt < 4; ++nt) {
            bf16x8 b0 = *(const bf16x8*)&ks[nt * 16 + col][quad * 8];
            bf16x8 b1 = *(const bf16x8*)&ks[nt * 16 + col][32 + quad * 8];
            f32x4 sc = {0.f, 0.f, 0.f, 0.f};
            sc = __builtin_amdgcn_mfma_f32_16x16x32_bf16(qf0, b0, sc, 0, 0, 0);
            sc = __builtin_amdgcn_mfma_f32_16x16x32_bf16(qf1, b1, sc, 0, 0, 0);
            int p = (cb << 6) + nt * 16 + col;
            #pragma unroll
            for (int g = 0; g < 4; ++g) {
                float w = weightf<SEL>(p, tq[g], mk0[g], mk1[g]);
                float s = sc[g] * 0.125f;
                float ev = (w > 0.0f) ? w * expf(s - M[g]) : 0.0f;
                l[g] += ev;
                ps[quad * 4 + g][nt * 16 + col] = ev;   // P in (row,col) layout
            }
        }
        // PV: A = P (query x pos), B = Vt (dim x pos).  ps is per-wave — no
        // barrier needed; compiler orders via lgkmcnt within the wave.
        float4 p0 = *(const float4*)&ps[col][quad * 8];
        float4 p1 = *(const float4*)&ps[col][quad * 8 + 4];
        float4 p2 = *(const float4*)&ps[col][32 + quad * 8];
        float4 p3 = *(const float4*)&ps[col][32 + quad * 8 + 4];
        bf16x8 ap0 = cvt8(p0, p1);
        bf16x8 ap1 = cvt8(p2, p3);
        #pragma unroll
        for (int nt = 0; nt < 4; ++nt) {
            bf16x8 bv0 = *(const bf16x8*)&vt[nt * 16 + col][quad * 8];
            bf16x8 bv1 = *(const bf16x8*)&vt[nt * 16 + col][32 + quad * 8];
            O[nt] = __builtin_amdgcn_mfma_f32_16x16x32_bf16(ap0, bv0, O[nt], 0, 0, 0);
            O[nt] = __builtin_amdgcn_mfma_f32_16x16x32_bf16(ap1, bv1, O[nt], 0, 0, 0);
        }
    }
    #pragma unroll
    for (int g = 0; g < 4; ++g) {
        l[g] += __shfl_xor(l[g], 1);
        l[g] += __shfl_xor(l[g], 2);
        l[g] += __shfl_xor(l[g], 4);
        l[g] += __shfl_xor(l[g], 8);
        float inv = 1.0f / l[g];
        #pragma unroll
        for (int nt = 0; nt < 4; ++nt) O[nt][g] *= inv;
    }
}

// ---------------------------------------------------------------------------
// Flash kernel: grid (64, 4); block = 16-query tile × kv-head; wave = rep.
// sel = weighted scan of positions 0..t (count weights); win = sliding window.
// Combines with ocmp_ws + gates and writes final output.
// ---------------------------------------------------------------------------
__global__ __launch_bounds__(256) void nsa_flash(
    const float* __restrict__ q, const float* __restrict__ gates_lin,
    const float* __restrict__ k_slc, const float* __restrict__ v_slc,
    const float* __restrict__ k_win, const float* __restrict__ v_win,
    const float* __restrict__ ocmp_ws, const unsigned int* __restrict__ selmask_ws,
    float* __restrict__ out)
{
    const int t0 = blockIdx.x * TQ;
    const int k  = blockIdx.y;
    const int tid = threadIdx.x, lane = tid & 63, r = tid >> 6;
    const int quad = lane >> 4, col = lane & 15;

    __shared__ unsigned short qs[REP][TQ][72];
    __shared__ unsigned short ks[64][72];
    __shared__ unsigned short vt[64][88];
    __shared__ float ps[REP][TQ][76];
    __shared__ unsigned int selm[TQ][2];

    // stage Q (bf16): each wave stages its own rep
    {
        int qrow = lane >> 2, dseg = lane & 3;
        const float* src = q + ((r * NKV + k) * T_LEN + t0 + qrow) * DH + dseg * 16;
        float4 a0 = *(const float4*)src,       a1 = *(const float4*)(src + 4);
        float4 a2 = *(const float4*)(src + 8), a3 = *(const float4*)(src + 12);
        *(bf16x8*)&qs[r][qrow][dseg * 16]     = cvt8(a0, a1);
        *(bf16x8*)&qs[r][qrow][dseg * 16 + 8] = cvt8(a2, a3);
    }
    if (tid < TQ) {
        selm[tid][0] = selmask_ws[(k * T_LEN + t0 + tid) * 2 + 0];
        selm[tid][1] = selmask_ws[(k * T_LEN + t0 + tid) * 2 + 1];
    }
    __syncthreads();

    // Q fragments (A-operand layout: m=lane&15, k=quad*8+j) — fixed all kernel
    bf16x8 qf0 = *(const bf16x8*)&qs[r][col][quad * 8];
    bf16x8 qf1 = *(const bf16x8*)&qs[r][col][32 + quad * 8];

    const int tmax = t0 + TQ - 1;
    f32x4 Osel[4], Owin[4];
    flash_branch<true>(k_slc, v_slc, k, t0, 0, tmax >> 6, tid, quad, col,
                       qf0, qf1, ks, vt, ps[r], selm, Osel);
    {
        int wlo = t0 - 255; if (wlo < 0) wlo = 0;
        flash_branch<false>(k_win, v_win, k, t0, wlo >> 6, tmax >> 6, tid, quad, col,
                            qf0, qf1, ks, vt, ps[r], selm, Owin);
    }

    // gating + combine with compressed branch
    const int hq = r * NKV + k;
    #pragma unroll
    for (int g = 0; g < 4; ++g) {
        int tq = t0 + quad * 4 + g;
        const float* gl = gates_lin + tq * 48 + hq * 3;
        float g0 = sigmoidf(gl[0]);
        float g1 = sigmoidf(gl[1]);
        float g2 = sigmoidf(gl[2]);
        #pragma unroll
        for (int nt = 0; nt < 4; ++nt) {
            int d = nt * 16 + col;
            int idx = (hq * T_LEN + tq) * DH + d;
            out[idx] = g0 * ocmp_ws[idx] + g1 * Osel[nt][g] + g2 * Owin[nt][g];
        }
    }
}

extern "C" void kernel_launch(void* const* d_in, const int* in_sizes, int n_in,
                              void* d_out, int out_size, void* d_ws, size_t ws_size,
                              hipStream_t stream) {
    const float* x         = (const float*)d_in[0];
    const float* q         = (const float*)d_in[1];
    const float* gate_w    = (const float*)d_in[2];
    const float* gate_b    = (const float*)d_in[3];
    const float* wk_cmp    = (const float*)d_in[4];
    const float* wv_cmp    = (const float*)d_in[5];
    const float* wk_slc    = (const float*)d_in[6];
    const float* wv_slc    = (const float*)d_in[7];
    const float* wk_win    = (const float*)d_in[8];
    const float* wv_win    = (const float*)d_in[9];
    const float* block_pos = (const float*)d_in[10];
    const float* ck1_w     = (const float*)d_in[11];
    const float* ck1_b     = (const float*)d_in[12];
    const float* ck2_w     = (const float*)d_in[13];
    const float* ck2_b     = (const float*)d_in[14];
    const float* cv1_w     = (const float*)d_in[15];
    const float* cv1_b     = (const float*)d_in[16];
    const float* cv2_w     = (const float*)d_in[17];
    const float* cv2_b     = (const float*)d_in[18];
    float* out = (float*)d_out;

    float* ws = (float*)d_ws;
    float* gates_lin = ws;                         // 1024*48
    float* k_cmp = gates_lin + T_LEN * 48;         // 1024*256 each
    float* v_cmp = k_cmp + T_LEN * KVD;
    float* k_slc = v_cmp + T_LEN * KVD;
    float* v_slc = k_slc + T_LEN * KVD;
    float* k_win = v_slc + T_LEN * KVD;
    float* v_win = k_win + T_LEN * KVD;
    float* ksum  = v_win + T_LEN * KVD;            // 63*4*64 each
    float* vsum  = ksum + NB * KVD;
    float* ocmp_ws = vsum + NB * KVD;              // 16*1024*64
    unsigned int* selmask_ws = (unsigned int*)(ocmp_ws + 16 * T_LEN * DH); // 4*1024*2

    dim3 blk(256);
    size_t smem_bytes = 2 * 32 * 68 * sizeof(float);
    proj_all<<<dim3(25, 16), blk, smem_bytes, stream>>>(
        x, gate_w, gate_b, wk_cmp, wv_cmp, wk_slc, wv_slc, wk_win, wv_win,
        gates_lin, k_cmp, v_cmp, k_slc, v_slc, k_win, v_win);
    nsa_summarize<<<dim3(NB, NKV, 2), blk, 0, stream>>>(
        k_cmp, v_cmp, block_pos,
        ck1_w, ck1_b, ck2_w, ck2_b, cv1_w, cv1_b, cv2_w, cv2_b,
        ksum, vsum);
    nsa_cmp<<<dim3(T_LEN, NKV), blk, 0, stream>>>(
        q, ksum, vsum, ocmp_ws, selmask_ws);
    nsa_flash<<<dim3(T_LEN / TQ, NKV), blk, 0, stream>>>(
        q, gates_lin, k_slc, v_slc, k_win, v_win, ocmp_ws, selmask_ws, out);
}

// Round 11
// 269.054 us; speedup vs baseline: 16.0384x; 1.0740x over previous
//
#include <hip/hip_runtime.h>
#include <hip/hip_bf16.h>
#include <math.h>

#define T_LEN 1024
#define D_MODEL 1024
#define NKV 4
#define REP 4
#define DH 64
#define NB 63
#define TOPN 8
#define KVD 256        // NKV*DH
#define LDIM2 1328     // virtual concatenated width without k_cmp
#define TQ 16          // query tile for flash kernel

typedef __attribute__((ext_vector_type(8))) short bf16x8;
typedef __attribute__((ext_vector_type(4))) float f32x4;

__device__ __forceinline__ float gelu_exact(float x) {
    return 0.5f * x * (1.0f + erff(x * 0.70710678118654752f));
}
__device__ __forceinline__ float sigmoidf(float x) {
    return 1.0f / (1.0f + expf(-x));
}
// pack 8 f32 -> 8 bf16 via HW v_cvt_pk_bf16_f32 (RNE)
__device__ __forceinline__ bf16x8 cvt8(float4 a0, float4 a1) {
    union { __hip_bfloat162 v; short2 s; } u0, u1, u2, u3;
    u0.v = __float22bfloat162_rn(make_float2(a0.x, a0.y));
    u1.v = __float22bfloat162_rn(make_float2(a0.z, a0.w));
    u2.v = __float22bfloat162_rn(make_float2(a1.x, a1.y));
    u3.v = __float22bfloat162_rn(make_float2(a1.z, a1.w));
    bf16x8 r;
    r[0] = u0.s.x; r[1] = u0.s.y; r[2] = u1.s.x; r[3] = u1.s.y;
    r[4] = u2.s.x; r[5] = u2.s.y; r[6] = u3.s.x; r[7] = u3.s.y;
    return r;
}

// ---------------------------------------------------------------------------
// Merged projection dispatch, grid (25,16), dynamic LDS 17408 B (unchanged).
// ---------------------------------------------------------------------------
__global__ __launch_bounds__(256) void proj_all(
    const float* __restrict__ x,
    const float* __restrict__ gate_w, const float* __restrict__ gate_b,
    const float* __restrict__ wk_cmp, const float* __restrict__ wv_cmp,
    const float* __restrict__ wk_slc, const float* __restrict__ wv_slc,
    const float* __restrict__ wk_win, const float* __restrict__ wv_win,
    float* __restrict__ gates_lin, float* __restrict__ k_cmp,
    float* __restrict__ v_cmp,
    float* __restrict__ k_slc, float* __restrict__ v_slc,
    float* __restrict__ k_win, float* __restrict__ v_win)
{
    extern __shared__ char smem[];
    const int tid = threadIdx.x;
    const int m0 = blockIdx.y * 64;

    if (blockIdx.x < 21) {
        typedef unsigned short row40[40];
        row40* As = (row40*)smem;
        row40* Bs = (row40*)(smem + 64 * 40 * sizeof(unsigned short));
        const int lane = tid & 63;
        const int w = tid >> 6;
        const int n0 = blockIdx.x * 64;

        const int srow = tid >> 2;
        const int sseg = tid & 3;
        const float* ga = x + (m0 + srow) * D_MODEL + sseg * 8;
        const float* gb;
        {
            int nn = n0 + srow;
            if (nn < 48)        gb = gate_w + nn * D_MODEL;
            else if (nn < 304)  gb = wv_cmp + (nn - 48) * D_MODEL;
            else if (nn < 560)  gb = wk_slc + (nn - 304) * D_MODEL;
            else if (nn < 816)  gb = wv_slc + (nn - 560) * D_MODEL;
            else if (nn < 1072) gb = wk_win + (nn - 816) * D_MODEL;
            else if (nn < 1328) gb = wv_win + (nn - 1072) * D_MODEL;
            else                gb = gate_w;
            gb += sseg * 8;
        }

        f32x4 acc[4] = {};
        const int arow = (w << 4) + (lane & 15);
        const int kk8  = (lane >> 4) * 8;

        for (int k0 = 0; k0 < D_MODEL; k0 += 32) {
            float4 a0 = *(const float4*)(ga + k0);
            float4 a1 = *(const float4*)(ga + k0 + 4);
            float4 b0 = *(const float4*)(gb + k0);
            float4 b1 = *(const float4*)(gb + k0 + 4);
            bf16x8 ap = cvt8(a0, a1);
            bf16x8 bp = cvt8(b0, b1);
            __syncthreads();
            *(bf16x8*)&As[srow][sseg * 8] = ap;
            *(bf16x8*)&Bs[srow][sseg * 8] = bp;
            __syncthreads();
            bf16x8 af = *(bf16x8*)&As[arow][kk8];
            #pragma unroll
            for (int j = 0; j < 4; ++j) {
                bf16x8 bfr = *(bf16x8*)&Bs[j * 16 + (lane & 15)][kk8];
                acc[j] = __builtin_amdgcn_mfma_f32_16x16x32_bf16(af, bfr, acc[j], 0, 0, 0);
            }
        }

        #pragma unroll
        for (int j = 0; j < 4; ++j) {
            int col = n0 + j * 16 + (lane & 15);
            if (col >= LDIM2) continue;
            int rbase = m0 + (w << 4) + (lane >> 4) * 4;
            float* dst; int cc; int stride = 256; float badd = 0.0f;
            if (col < 48)        { dst = gates_lin; cc = col;        stride = 48; badd = gate_b[col]; }
            else if (col < 304)  { dst = v_cmp;     cc = col - 48;   }
            else if (col < 560)  { dst = k_slc;     cc = col - 304;  }
            else if (col < 816)  { dst = v_slc;     cc = col - 560;  }
            else if (col < 1072) { dst = k_win;     cc = col - 816;  }
            else                 { dst = v_win;     cc = col - 1072; }
            #pragma unroll
            for (int rg = 0; rg < 4; ++rg)
                dst[(rbase + rg) * stride + cc] = acc[j][rg] + badd;
        }
    } else {
        typedef float row68[68];
        row68* As = (row68*)smem;
        row68* Bs = (row68*)(smem + 32 * 68 * sizeof(float));
        const int tx = tid & 15, ty = tid >> 4;
        const int n0 = (blockIdx.x - 21) * 64;
        const int srow = tid >> 2, sseg = tid & 3;
        const float* ga = x + (m0 + srow) * D_MODEL + sseg * 8;
        const float* gb = wk_cmp + (n0 + srow) * D_MODEL + sseg * 8;

        float acc[4][4] = {};
        for (int k0 = 0; k0 < D_MODEL; k0 += 32) {
            float4 a0 = *(const float4*)(ga + k0);
            float4 a1 = *(const float4*)(ga + k0 + 4);
            float4 b0 = *(const float4*)(gb + k0);
            float4 b1 = *(const float4*)(gb + k0 + 4);
            __syncthreads();
            As[sseg*8+0][srow]=a0.x; As[sseg*8+1][srow]=a0.y; As[sseg*8+2][srow]=a0.z; As[sseg*8+3][srow]=a0.w;
            As[sseg*8+4][srow]=a1.x; As[sseg*8+5][srow]=a1.y; As[sseg*8+6][srow]=a1.z; As[sseg*8+7][srow]=a1.w;
            Bs[sseg*8+0][srow]=b0.x; Bs[sseg*8+1][srow]=b0.y; Bs[sseg*8+2][srow]=b0.z; Bs[sseg*8+3][srow]=b0.w;
            Bs[sseg*8+4][srow]=b1.x; Bs[sseg*8+5][srow]=b1.y; Bs[sseg*8+6][srow]=b1.z; Bs[sseg*8+7][srow]=b1.w;
            __syncthreads();
            #pragma unroll
            for (int kk = 0; kk < 32; ++kk) {
                float4 a4 = *(const float4*)&As[kk][ty * 4];
                float4 b4 = *(const float4*)&Bs[kk][tx * 4];
                acc[0][0] += a4.x*b4.x; acc[0][1] += a4.x*b4.y; acc[0][2] += a4.x*b4.z; acc[0][3] += a4.x*b4.w;
                acc[1][0] += a4.y*b4.x; acc[1][1] += a4.y*b4.y; acc[1][2] += a4.y*b4.z; acc[1][3] += a4.y*b4.w;
                acc[2][0] += a4.z*b4.x; acc[2][1] += a4.z*b4.y; acc[2][2] += a4.z*b4.z; acc[2][3] += a4.z*b4.w;
                acc[3][0] += a4.w*b4.x; acc[3][1] += a4.w*b4.y; acc[3][2] += a4.w*b4.z; acc[3][3] += a4.w*b4.w;
            }
        }
        #pragma unroll
        for (int i = 0; i < 4; ++i) {
            int mm = m0 + ty * 4 + i;
            #pragma unroll
            for (int j = 0; j < 4; ++j)
                k_cmp[mm * KVD + n0 + tx * 4 + j] = acc[i][j];
        }
    }
}

// ---------------------------------------------------------------------------
// Block summaries (unchanged). grid (63,4,2).
// ---------------------------------------------------------------------------
__global__ __launch_bounds__(256) void nsa_summarize(
    const float* __restrict__ k_cmp, const float* __restrict__ v_cmp,
    const float* __restrict__ block_pos,
    const float* __restrict__ ck1_w, const float* __restrict__ ck1_b,
    const float* __restrict__ ck2_w, const float* __restrict__ ck2_b,
    const float* __restrict__ cv1_w, const float* __restrict__ cv1_b,
    const float* __restrict__ cv2_w, const float* __restrict__ cv2_b,
    float* __restrict__ ksum, float* __restrict__ vsum)
{
    const int n = blockIdx.x, k = blockIdx.y, which = blockIdx.z;
    const float* src = which ? v_cmp : k_cmp;
    const float* w1  = which ? cv1_w : ck1_w;
    const float* b1  = which ? cv1_b : ck1_b;
    const float* w2  = which ? cv2_w : ck2_w;
    const float* b2  = which ? cv2_b : ck2_b;
    float* dst       = which ? vsum  : ksum;

    __shared__ float flat[4 * 516];
    __shared__ float hidden[DH];
    const int tid = threadIdx.x;
    const int start = n * 16;

    for (int e = tid; e < 512; e += 256) {
        int p = e >> 4, d4 = e & 15;
        float4 s = *(const float4*)(src + ((start + p) * NKV + k) * DH + d4 * 4);
        float4 bp = *(const float4*)(block_pos + p * DH + d4 * 4);
        float4 r; r.x = s.x + bp.x; r.y = s.y + bp.y; r.z = s.z + bp.z; r.w = s.w + bp.w;
        *(float4*)&flat[(p >> 3) * 516 + (p & 7) * 64 + d4 * 4] = r;
    }
    __syncthreads();
    {
        int h = tid >> 2, part = tid & 3;
        const float* wr = w1 + h * 2048 + part * 512;
        const float* fl = flat + part * 516;
        float s = 0.0f;
        for (int j = 0; j < 512; j += 4) {
            float4 a = *(const float4*)(fl + j);
            float4 b = *(const float4*)(wr + j);
            s += a.x * b.x + a.y * b.y + a.z * b.z + a.w * b.w;
        }
        s += __shfl_xor(s, 1);
        s += __shfl_xor(s, 2);
        if (part == 0) hidden[h] = gelu_exact(s + b1[h]);
    }
    __syncthreads();
    {
        int dh = tid >> 2, part = tid & 3;
        const float* wr = w2 + dh * 64 + part * 16;
        float s = 0.0f;
        #pragma unroll
        for (int hh = 0; hh < 16; ++hh) s += hidden[part * 16 + hh] * wr[hh];
        s += __shfl_xor(s, 1);
        s += __shfl_xor(s, 2);
        if (part == 0) dst[(n * NKV + k) * DH + dh] = s + b2[dh];
    }
}

// ---------------------------------------------------------------------------
// Compressed branch + top-8 selection (f32, selection exact). LDS-staged
// ksum/vsum (r5-proven pattern — r10 version regressed to global gathers).
// Writes out = g0*ocmp (flash adds the other branches on top, stream-ordered).
// grid (1024, 4).
// ---------------------------------------------------------------------------
__global__ __launch_bounds__(256) void nsa_cmp(
    const float* __restrict__ q, const float* __restrict__ gates_lin,
    const float* __restrict__ ksum, const float* __restrict__ vsum,
    float* __restrict__ out, unsigned int* __restrict__ selmask_ws)
{
    const int t = blockIdx.x, k = blockIdx.y;
    const int tid = threadIdx.x, lane = tid & 63, r = tid >> 6;

    __shared__ float q_s[REP][DH];
    __shared__ float chunk[64][66];
    __shared__ float p_cmp_s[REP][64];

    q_s[r][lane] = q[((r * NKV + k) * T_LEN + t) * DH + lane];
    for (int e = tid; e < 64 * 32; e += 256) {
        int p = e >> 5, d2 = e & 31;
        int nn = (p < NB) ? p : NB - 1;
        *(float2*)&chunk[p][d2 * 2] = *(const float2*)(ksum + (nn * NKV + k) * DH + d2 * 2);
    }
    __syncthreads();

    float s = -1e30f;
    if (lane < NB && (lane * 16 + 31) <= t) {
        float acc = 0.0f;
        #pragma unroll 8
        for (int d2 = 0; d2 < 32; ++d2) {
            float2 qd = *(const float2*)&q_s[r][d2 * 2];
            float2 cd = *(const float2*)&chunk[lane][d2 * 2];
            acc += qd.x * cd.x + qd.y * cd.y;
        }
        s = acc * 0.125f;
    }
    float m = s;
    for (int off = 32; off; off >>= 1) m = fmaxf(m, __shfl_xor(m, off));
    float e = (lane < NB) ? expf(s - m) : 0.0f;
    float sum = e;
    for (int off = 32; off; off >>= 1) sum += __shfl_xor(sum, off);
    p_cmp_s[r][lane] = (lane < NB) ? (e / sum) : 0.0f;
    __syncthreads();

    // stage vsum (all threads), then top-8 on wave 0 (p_cmp_s untouched)
    for (int e2 = tid; e2 < 64 * 32; e2 += 256) {
        int p = e2 >> 5, d2 = e2 & 31;
        int nn = (p < NB) ? p : NB - 1;
        *(float2*)&chunk[p][d2 * 2] = *(const float2*)(vsum + (nn * NKV + k) * DH + d2 * 2);
    }
    if (r == 0) {
        float imp = (lane < NB)
            ? (p_cmp_s[0][lane] + p_cmp_s[1][lane] + p_cmp_s[2][lane] + p_cmp_s[3][lane])
            : -1e30f;
        unsigned long long msk = 0ull;
        for (int it = 0; it < TOPN; ++it) {
            float v = imp; int i = lane;
            for (int off = 32; off; off >>= 1) {
                float ov = __shfl_xor(v, off);
                int   oi = __shfl_xor(i, off);
                if (ov > v || (ov == v && oi < i)) { v = ov; i = oi; }
            }
            msk |= 1ull << i;           // wave-uniform after butterfly
            if (lane == i) imp = -1e30f;
        }
        if (lane == 0) {
            selmask_ws[(k * T_LEN + t) * 2 + 0] = (unsigned int)(msk & 0xffffffffu);
            selmask_ws[(k * T_LEN + t) * 2 + 1] = (unsigned int)(msk >> 32);
        }
    }
    __syncthreads();

    float ocmp = 0.0f;
    if (t >= 31) {
        #pragma unroll 4
        for (int n = 0; n < NB; ++n)
            ocmp += p_cmp_s[r][n] * chunk[n][lane];
    }
    const int hq = r * NKV + k;
    float g0 = sigmoidf(gates_lin[t * 48 + hq * 3]);
    out[(hq * T_LEN + t) * DH + lane] = g0 * ocmp;
}

// ---------------------------------------------------------------------------
// Flash machinery (round-10-proven). sel: position p belongs to block b iff
// b ∈ {p>>4, (p>>4)-1}; weight = membership count ∈ {0,1,2} (duplicates
// contribute with multiplicity). Two-sweep fixed-M softmax.
// ---------------------------------------------------------------------------
template<bool SEL>
__device__ __forceinline__ float weightf(int p, int tq, unsigned mk0, unsigned mk1) {
    if (SEL) {
        int b = p >> 4;
        unsigned c = (b < 32) ? ((mk0 >> b) & 1u) : ((mk1 >> (b - 32)) & 1u);
        int b2 = b - 1;
        if (b2 >= 0)
            c += (b2 < 32) ? ((mk0 >> b2) & 1u) : ((mk1 >> (b2 - 32)) & 1u);
        return (p <= tq) ? (float)c : 0.0f;
    } else {
        return (p <= tq && p > tq - 256) ? 1.0f : 0.0f;
    }
}

__device__ __forceinline__ void stage_k_bf16(const float* kptr, int k, int cb, int tid,
                                             unsigned short (*ks)[72]) {
    int row = tid >> 2, dseg = tid & 3;
    const float* src = kptr + (((cb << 6) + row) * NKV + k) * DH + dseg * 16;
    float4 a0 = *(const float4*)(src);
    float4 a1 = *(const float4*)(src + 4);
    float4 a2 = *(const float4*)(src + 8);
    float4 a3 = *(const float4*)(src + 12);
    *(bf16x8*)&ks[row][dseg * 16]     = cvt8(a0, a1);
    *(bf16x8*)&ks[row][dseg * 16 + 8] = cvt8(a2, a3);
}

__device__ __forceinline__ void stage_v_t(const float* vptr, int k, int cb, int tid,
                                          unsigned short (*vt)[88]) {
    int l = tid & 63, wv = tid >> 6;
    int dbase = wv * 16 + ((l >> 5) << 3);    // 8 dims per thread
    int pp = (l & 31) * 2;                    // position pair
    const float* v0 = vptr + (((cb << 6) + pp) * NKV + k) * DH + dbase;
    const float* v1 = v0 + NKV * DH;
    float4 x0 = *(const float4*)v0, x1 = *(const float4*)(v0 + 4);
    float4 y0 = *(const float4*)v1, y1 = *(const float4*)(v1 + 4);
    union { __hip_bfloat162 v; unsigned u; } t_;
    t_.v = __float22bfloat162_rn(make_float2(x0.x, y0.x)); *(unsigned*)&vt[dbase + 0][pp] = t_.u;
    t_.v = __float22bfloat162_rn(make_float2(x0.y, y0.y)); *(unsigned*)&vt[dbase + 1][pp] = t_.u;
    t_.v = __float22bfloat162_rn(make_float2(x0.z, y0.z)); *(unsigned*)&vt[dbase + 2][pp] = t_.u;
    t_.v = __float22bfloat162_rn(make_float2(x0.w, y0.w)); *(unsigned*)&vt[dbase + 3][pp] = t_.u;
    t_.v = __float22bfloat162_rn(make_float2(x1.x, y1.x)); *(unsigned*)&vt[dbase + 4][pp] = t_.u;
    t_.v = __float22bfloat162_rn(make_float2(x1.y, y1.y)); *(unsigned*)&vt[dbase + 5][pp] = t_.u;
    t_.v = __float22bfloat162_rn(make_float2(x1.z, y1.z)); *(unsigned*)&vt[dbase + 6][pp] = t_.u;
    t_.v = __float22bfloat162_rn(make_float2(x1.w, y1.w)); *(unsigned*)&vt[dbase + 7][pp] = t_.u;
}

template<bool SEL>
__device__ __forceinline__ void flash_branch(
    const float* kptr, const float* vptr, int k, int t0, int c0, int c1,
    int tid, int quad, int col,
    bf16x8 qf0, bf16x8 qf1,
    unsigned short (*ks)[72], unsigned short (*vt)[88], float (*ps)[76],
    const unsigned int (*selm)[2],
    f32x4 (&O)[4])
{
    unsigned mk0[4] = {0,0,0,0}, mk1[4] = {0,0,0,0};
    int tq[4];
    #pragma unroll
    for (int g = 0; g < 4; ++g) {
        int row = quad * 4 + g;
        tq[g] = t0 + row;
        if (SEL) { mk0[g] = selm[row][0]; mk1[g] = selm[row][1]; }
    }

    // ---- sweep 1: exact masked max per query row ----
    float M[4] = {-1e30f, -1e30f, -1e30f, -1e30f};
    for (int cb = c0; cb <= c1; ++cb) {
        __syncthreads();
        stage_k_bf16(kptr, k, cb, tid, ks);
        __syncthreads();
        #pragma unroll
        for (int nt = 0; nt < 4; ++nt) {
            bf16x8 b0 = *(const bf16x8*)&ks[nt * 16 + col][quad * 8];
            bf16x8 b1 = *(const bf16x8*)&ks[nt * 16 + col][32 + quad * 8];
            f32x4 sc = {0.f, 0.f, 0.f, 0.f};
            sc = __builtin_amdgcn_mfma_f32_16x16x32_bf16(qf0, b0, sc, 0, 0, 0);
            sc = __builtin_amdgcn_mfma_f32_16x16x32_bf16(qf1, b1, sc, 0, 0, 0);
            int p = (cb << 6) + nt * 16 + col;
            #pragma unroll
            for (int g = 0; g < 4; ++g) {
                float w = weightf<SEL>(p, tq[g], mk0[g], mk1[g]);
                float s = sc[g] * 0.125f;
                if (w > 0.0f) M[g] = fmaxf(M[g], s);
            }
        }
    }
    #pragma unroll
    for (int g = 0; g < 4; ++g) {
        M[g] = fmaxf(M[g], __shfl_xor(M[g], 1));
        M[g] = fmaxf(M[g], __shfl_xor(M[g], 2));
        M[g] = fmaxf(M[g], __shfl_xor(M[g], 4));
        M[g] = fmaxf(M[g], __shfl_xor(M[g], 8));
    }

    // ---- sweep 2: exp / l / P·V with fixed M ----
    float l[4] = {0.f, 0.f, 0.f, 0.f};
    f32x4 z = {0.f, 0.f, 0.f, 0.f};
    O[0] = z; O[1] = z; O[2] = z; O[3] = z;

    for (int cb = c0; cb <= c1; ++cb) {
        __syncthreads();
        stage_k_bf16(kptr, k, cb, tid, ks);
        stage_v_t(vptr, k, cb, tid, vt);
        __syncthreads();
        #pragma unroll
        for (int nt = 0; nt < 4; ++nt) {
            bf16x8 b0 = *(const bf16x8*)&ks[nt * 16 + col][quad * 8];
            bf16x8 b1 = *(const bf16x8*)&ks[nt * 16 + col][32 + quad * 8];
            f32x4 sc = {0.f, 0.f, 0.f, 0.f};
            sc = __builtin_amdgcn_mfma_f32_16x16x32_bf16(qf0, b0, sc, 0, 0, 0);
            sc = __builtin_amdgcn_mfma_f32_16x16x32_bf16(qf1, b1, sc, 0, 0, 0);
            int p = (cb << 6) + nt * 16 + col;
            #pragma unroll
            for (int g = 0; g < 4; ++g) {
                float w = weightf<SEL>(p, tq[g], mk0[g], mk1[g]);
                float s = sc[g] * 0.125f;
                float ev = (w > 0.0f) ? w * expf(s - M[g]) : 0.0f;
                l[g] += ev;
                ps[quad * 4 + g][nt * 16 + col] = ev;   // P in (row,col) layout
            }
        }
        // PV: A = P (query x pos), B = Vt (dim x pos). ps is per-wave.
        float4 p0 = *(const float4*)&ps[col][quad * 8];
        float4 p1 = *(const float4*)&ps[col][quad * 8 + 4];
        float4 p2 = *(const float4*)&ps[col][32 + quad * 8];
        float4 p3 = *(const float4*)&ps[col][32 + quad * 8 + 4];
        bf16x8 ap0 = cvt8(p0, p1);
        bf16x8 ap1 = cvt8(p2, p3);
        #pragma unroll
        for (int nt = 0; nt < 4; ++nt) {
            bf16x8 bv0 = *(const bf16x8*)&vt[nt * 16 + col][quad * 8];
            bf16x8 bv1 = *(const bf16x8*)&vt[nt * 16 + col][32 + quad * 8];
            O[nt] = __builtin_amdgcn_mfma_f32_16x16x32_bf16(ap0, bv0, O[nt], 0, 0, 0);
            O[nt] = __builtin_amdgcn_mfma_f32_16x16x32_bf16(ap1, bv1, O[nt], 0, 0, 0);
        }
    }
    #pragma unroll
    for (int g = 0; g < 4; ++g) {
        l[g] += __shfl_xor(l[g], 1);
        l[g] += __shfl_xor(l[g], 2);
        l[g] += __shfl_xor(l[g], 4);
        l[g] += __shfl_xor(l[g], 8);
        float inv = 1.0f / l[g];
        #pragma unroll
        for (int nt = 0; nt < 4; ++nt) O[nt][g] *= inv;
    }
}

// ---------------------------------------------------------------------------
// Flash kernel: grid (64, 4, 2); z = branch (0=sel, 1=win). 512 blocks ->
// 2 blocks/CU co-resident (r10 had 256 blocks = 1/CU, occupancy 6.7%,
// latency-bound). Adds gated contribution into out via atomicAdd; nsa_cmp
// wrote out = g0*ocmp earlier in the stream.
// ---------------------------------------------------------------------------
__global__ __launch_bounds__(256) void nsa_flash(
    const float* __restrict__ q, const float* __restrict__ gates_lin,
    const float* __restrict__ k_slc, const float* __restrict__ v_slc,
    const float* __restrict__ k_win, const float* __restrict__ v_win,
    const unsigned int* __restrict__ selmask_ws,
    float* __restrict__ out)
{
    const int t0 = blockIdx.x * TQ;
    const int k  = blockIdx.y;
    const int br = blockIdx.z;          // 0 = selected, 1 = window
    const int tid = threadIdx.x, lane = tid & 63, r = tid >> 6;
    const int quad = lane >> 4, col = lane & 15;

    __shared__ unsigned short qs[REP][TQ][72];
    __shared__ unsigned short ks[64][72];
    __shared__ unsigned short vt[64][88];
    __shared__ float ps[REP][TQ][76];
    __shared__ unsigned int selm[TQ][2];

    // stage Q (bf16): each wave stages its own rep
    {
        int qrow = lane >> 2, dseg = lane & 3;
        const float* src = q + ((r * NKV + k) * T_LEN + t0 + qrow) * DH + dseg * 16;
        float4 a0 = *(const float4*)src,       a1 = *(const float4*)(src + 4);
        float4 a2 = *(const float4*)(src + 8), a3 = *(const float4*)(src + 12);
        *(bf16x8*)&qs[r][qrow][dseg * 16]     = cvt8(a0, a1);
        *(bf16x8*)&qs[r][qrow][dseg * 16 + 8] = cvt8(a2, a3);
    }
    if (tid < TQ) {
        selm[tid][0] = selmask_ws[(k * T_LEN + t0 + tid) * 2 + 0];
        selm[tid][1] = selmask_ws[(k * T_LEN + t0 + tid) * 2 + 1];
    }
    __syncthreads();

    // Q fragments (A-operand layout: m=lane&15, k=quad*8+j)
    bf16x8 qf0 = *(const bf16x8*)&qs[r][col][quad * 8];
    bf16x8 qf1 = *(const bf16x8*)&qs[r][col][32 + quad * 8];

    const int tmax = t0 + TQ - 1;
    f32x4 O[4];
    if (br == 0) {
        flash_branch<true>(k_slc, v_slc, k, t0, 0, tmax >> 6, tid, quad, col,
                           qf0, qf1, ks, vt, ps[r], selm, O);
    } else {
        int wlo = t0 - 255; if (wlo < 0) wlo = 0;
        flash_branch<false>(k_win, v_win, k, t0, wlo >> 6, tmax >> 6, tid, quad, col,
                            qf0, qf1, ks, vt, ps[r], selm, O);
    }

    // gated atomic accumulate (out already holds g0*ocmp)
    const int hq = r * NKV + k;
    #pragma unroll
    for (int g = 0; g < 4; ++g) {
        int tq = t0 + quad * 4 + g;
        float gg = sigmoidf(gates_lin[tq * 48 + hq * 3 + 1 + br]);
        #pragma unroll
        for (int nt = 0; nt < 4; ++nt) {
            int d = nt * 16 + col;
            atomicAdd(&out[(hq * T_LEN + tq) * DH + d], gg * O[nt][g]);
        }
    }
}

extern "C" void kernel_launch(void* const* d_in, const int* in_sizes, int n_in,
                              void* d_out, int out_size, void* d_ws, size_t ws_size,
                              hipStream_t stream) {
    const float* x         = (const float*)d_in[0];
    const float* q         = (const float*)d_in[1];
    const float* gate_w    = (const float*)d_in[2];
    const float* gate_b    = (const float*)d_in[3];
    const float* wk_cmp    = (const float*)d_in[4];
    const float* wv_cmp    = (const float*)d_in[5];
    const float* wk_slc    = (const float*)d_in[6];
    const float* wv_slc    = (const float*)d_in[7];
    const float* wk_win    = (const float*)d_in[8];
    const float* wv_win    = (const float*)d_in[9];
    const float* block_pos = (const float*)d_in[10];
    const float* ck1_w     = (const float*)d_in[11];
    const float* ck1_b     = (const float*)d_in[12];
    const float* ck2_w     = (const float*)d_in[13];
    const float* ck2_b     = (const float*)d_in[14];
    const float* cv1_w     = (const float*)d_in[15];
    const float* cv1_b     = (const float*)d_in[16];
    const float* cv2_w     = (const float*)d_in[17];
    const float* cv2_b     = (const float*)d_in[18];
    float* out = (float*)d_out;

    float* ws = (float*)d_ws;
    float* gates_lin = ws;                         // 1024*48
    float* k_cmp = gates_lin + T_LEN * 48;         // 1024*256 each
    float* v_cmp = k_cmp + T_LEN * KVD;
    float* k_slc = v_cmp + T_LEN * KVD;
    float* v_slc = k_slc + T_LEN * KVD;
    float* k_win = v_slc + T_LEN * KVD;
    float* v_win = k_win + T_LEN * KVD;
    float* ksum  = v_win + T_LEN * KVD;            // 63*4*64 each
    float* vsum  = ksum + NB * KVD;
    unsigned int* selmask_ws = (unsigned int*)(vsum + NB * KVD); // 4*1024*2

    dim3 blk(256);
    size_t smem_bytes = 2 * 32 * 68 * sizeof(float);
    proj_all<<<dim3(25, 16), blk, smem_bytes, stream>>>(
        x, gate_w, gate_b, wk_cmp, wv_cmp, wk_slc, wv_slc, wk_win, wv_win,
        gates_lin, k_cmp, v_cmp, k_slc, v_slc, k_win, v_win);
    nsa_summarize<<<dim3(NB, NKV, 2), blk, 0, stream>>>(
        k_cmp, v_cmp, block_pos,
        ck1_w, ck1_b, ck2_w, ck2_b, cv1_w, cv1_b, cv2_w, cv2_b,
        ksum, vsum);
    nsa_cmp<<<dim3(T_LEN, NKV), blk, 0, stream>>>(
        q, gates_lin, ksum, vsum, out, selmask_ws);
    nsa_flash<<<dim3(T_LEN / TQ, NKV, 2), blk, 0, stream>>>(
        q, gates_lin, k_slc, v_slc, k_win, v_win, selmask_ws, out);
}

// Round 12
// 253.074 us; speedup vs baseline: 17.0511x; 1.0631x over previous
//
#include <hip/hip_runtime.h>
#include <hip/hip_bf16.h>
#include <math.h>

#define T_LEN 1024
#define D_MODEL 1024
#define NKV 4
#define REP 4
#define DH 64
#define NB 63
#define TOPN 8
#define KVD 256        // NKV*DH
#define LDIM2 1328     // virtual concatenated width without k_cmp
#define TQ 16          // query tile for flash kernel
#define T4 4           // query tile for cmp kernel

typedef __attribute__((ext_vector_type(8))) short bf16x8;
typedef __attribute__((ext_vector_type(4))) float f32x4;

__device__ __forceinline__ float gelu_exact(float x) {
    return 0.5f * x * (1.0f + erff(x * 0.70710678118654752f));
}
__device__ __forceinline__ float sigmoidf(float x) {
    return 1.0f / (1.0f + expf(-x));
}
// pack 8 f32 -> 8 bf16 via HW v_cvt_pk_bf16_f32 (RNE)
__device__ __forceinline__ bf16x8 cvt8(float4 a0, float4 a1) {
    union { __hip_bfloat162 v; short2 s; } u0, u1, u2, u3;
    u0.v = __float22bfloat162_rn(make_float2(a0.x, a0.y));
    u1.v = __float22bfloat162_rn(make_float2(a0.z, a0.w));
    u2.v = __float22bfloat162_rn(make_float2(a1.x, a1.y));
    u3.v = __float22bfloat162_rn(make_float2(a1.z, a1.w));
    bf16x8 r;
    r[0] = u0.s.x; r[1] = u0.s.y; r[2] = u1.s.x; r[3] = u1.s.y;
    r[4] = u2.s.x; r[5] = u2.s.y; r[6] = u3.s.x; r[7] = u3.s.y;
    return r;
}

// ---------------------------------------------------------------------------
// Merged projection dispatch, grid (25,16), dynamic LDS 17408 B (unchanged).
// ---------------------------------------------------------------------------
__global__ __launch_bounds__(256) void proj_all(
    const float* __restrict__ x,
    const float* __restrict__ gate_w, const float* __restrict__ gate_b,
    const float* __restrict__ wk_cmp, const float* __restrict__ wv_cmp,
    const float* __restrict__ wk_slc, const float* __restrict__ wv_slc,
    const float* __restrict__ wk_win, const float* __restrict__ wv_win,
    float* __restrict__ gates_lin, float* __restrict__ k_cmp,
    float* __restrict__ v_cmp,
    float* __restrict__ k_slc, float* __restrict__ v_slc,
    float* __restrict__ k_win, float* __restrict__ v_win)
{
    extern __shared__ char smem[];
    const int tid = threadIdx.x;
    const int m0 = blockIdx.y * 64;

    if (blockIdx.x < 21) {
        typedef unsigned short row40[40];
        row40* As = (row40*)smem;
        row40* Bs = (row40*)(smem + 64 * 40 * sizeof(unsigned short));
        const int lane = tid & 63;
        const int w = tid >> 6;
        const int n0 = blockIdx.x * 64;

        const int srow = tid >> 2;
        const int sseg = tid & 3;
        const float* ga = x + (m0 + srow) * D_MODEL + sseg * 8;
        const float* gb;
        {
            int nn = n0 + srow;
            if (nn < 48)        gb = gate_w + nn * D_MODEL;
            else if (nn < 304)  gb = wv_cmp + (nn - 48) * D_MODEL;
            else if (nn < 560)  gb = wk_slc + (nn - 304) * D_MODEL;
            else if (nn < 816)  gb = wv_slc + (nn - 560) * D_MODEL;
            else if (nn < 1072) gb = wk_win + (nn - 816) * D_MODEL;
            else if (nn < 1328) gb = wv_win + (nn - 1072) * D_MODEL;
            else                gb = gate_w;
            gb += sseg * 8;
        }

        f32x4 acc[4] = {};
        const int arow = (w << 4) + (lane & 15);
        const int kk8  = (lane >> 4) * 8;

        for (int k0 = 0; k0 < D_MODEL; k0 += 32) {
            float4 a0 = *(const float4*)(ga + k0);
            float4 a1 = *(const float4*)(ga + k0 + 4);
            float4 b0 = *(const float4*)(gb + k0);
            float4 b1 = *(const float4*)(gb + k0 + 4);
            bf16x8 ap = cvt8(a0, a1);
            bf16x8 bp = cvt8(b0, b1);
            __syncthreads();
            *(bf16x8*)&As[srow][sseg * 8] = ap;
            *(bf16x8*)&Bs[srow][sseg * 8] = bp;
            __syncthreads();
            bf16x8 af = *(bf16x8*)&As[arow][kk8];
            #pragma unroll
            for (int j = 0; j < 4; ++j) {
                bf16x8 bfr = *(bf16x8*)&Bs[j * 16 + (lane & 15)][kk8];
                acc[j] = __builtin_amdgcn_mfma_f32_16x16x32_bf16(af, bfr, acc[j], 0, 0, 0);
            }
        }

        #pragma unroll
        for (int j = 0; j < 4; ++j) {
            int col = n0 + j * 16 + (lane & 15);
            if (col >= LDIM2) continue;
            int rbase = m0 + (w << 4) + (lane >> 4) * 4;
            float* dst; int cc; int stride = 256; float badd = 0.0f;
            if (col < 48)        { dst = gates_lin; cc = col;        stride = 48; badd = gate_b[col]; }
            else if (col < 304)  { dst = v_cmp;     cc = col - 48;   }
            else if (col < 560)  { dst = k_slc;     cc = col - 304;  }
            else if (col < 816)  { dst = v_slc;     cc = col - 560;  }
            else if (col < 1072) { dst = k_win;     cc = col - 816;  }
            else                 { dst = v_win;     cc = col - 1072; }
            #pragma unroll
            for (int rg = 0; rg < 4; ++rg)
                dst[(rbase + rg) * stride + cc] = acc[j][rg] + badd;
        }
    } else {
        typedef float row68[68];
        row68* As = (row68*)smem;
        row68* Bs = (row68*)(smem + 32 * 68 * sizeof(float));
        const int tx = tid & 15, ty = tid >> 4;
        const int n0 = (blockIdx.x - 21) * 64;
        const int srow = tid >> 2, sseg = tid & 3;
        const float* ga = x + (m0 + srow) * D_MODEL + sseg * 8;
        const float* gb = wk_cmp + (n0 + srow) * D_MODEL + sseg * 8;

        float acc[4][4] = {};
        for (int k0 = 0; k0 < D_MODEL; k0 += 32) {
            float4 a0 = *(const float4*)(ga + k0);
            float4 a1 = *(const float4*)(ga + k0 + 4);
            float4 b0 = *(const float4*)(gb + k0);
            float4 b1 = *(const float4*)(gb + k0 + 4);
            __syncthreads();
            As[sseg*8+0][srow]=a0.x; As[sseg*8+1][srow]=a0.y; As[sseg*8+2][srow]=a0.z; As[sseg*8+3][srow]=a0.w;
            As[sseg*8+4][srow]=a1.x; As[sseg*8+5][srow]=a1.y; As[sseg*8+6][srow]=a1.z; As[sseg*8+7][srow]=a1.w;
            Bs[sseg*8+0][srow]=b0.x; Bs[sseg*8+1][srow]=b0.y; Bs[sseg*8+2][srow]=b0.z; Bs[sseg*8+3][srow]=b0.w;
            Bs[sseg*8+4][srow]=b1.x; Bs[sseg*8+5][srow]=b1.y; Bs[sseg*8+6][srow]=b1.z; Bs[sseg*8+7][srow]=b1.w;
            __syncthreads();
            #pragma unroll
            for (int kk = 0; kk < 32; ++kk) {
                float4 a4 = *(const float4*)&As[kk][ty * 4];
                float4 b4 = *(const float4*)&Bs[kk][tx * 4];
                acc[0][0] += a4.x*b4.x; acc[0][1] += a4.x*b4.y; acc[0][2] += a4.x*b4.z; acc[0][3] += a4.x*b4.w;
                acc[1][0] += a4.y*b4.x; acc[1][1] += a4.y*b4.y; acc[1][2] += a4.y*b4.z; acc[1][3] += a4.y*b4.w;
                acc[2][0] += a4.z*b4.x; acc[2][1] += a4.z*b4.y; acc[2][2] += a4.z*b4.z; acc[2][3] += a4.z*b4.w;
                acc[3][0] += a4.w*b4.x; acc[3][1] += a4.w*b4.y; acc[3][2] += a4.w*b4.z; acc[3][3] += a4.w*b4.w;
            }
        }
        #pragma unroll
        for (int i = 0; i < 4; ++i) {
            int mm = m0 + ty * 4 + i;
            #pragma unroll
            for (int j = 0; j < 4; ++j)
                k_cmp[mm * KVD + n0 + tx * 4 + j] = acc[i][j];
        }
    }
}

// ---------------------------------------------------------------------------
// Block summaries (unchanged). grid (63,4,2).
// ---------------------------------------------------------------------------
__global__ __launch_bounds__(256) void nsa_summarize(
    const float* __restrict__ k_cmp, const float* __restrict__ v_cmp,
    const float* __restrict__ block_pos,
    const float* __restrict__ ck1_w, const float* __restrict__ ck1_b,
    const float* __restrict__ ck2_w, const float* __restrict__ ck2_b,
    const float* __restrict__ cv1_w, const float* __restrict__ cv1_b,
    const float* __restrict__ cv2_w, const float* __restrict__ cv2_b,
    float* __restrict__ ksum, float* __restrict__ vsum)
{
    const int n = blockIdx.x, k = blockIdx.y, which = blockIdx.z;
    const float* src = which ? v_cmp : k_cmp;
    const float* w1  = which ? cv1_w : ck1_w;
    const float* b1  = which ? cv1_b : ck1_b;
    const float* w2  = which ? cv2_w : ck2_w;
    const float* b2  = which ? cv2_b : ck2_b;
    float* dst       = which ? vsum  : ksum;

    __shared__ float flat[4 * 516];
    __shared__ float hidden[DH];
    const int tid = threadIdx.x;
    const int start = n * 16;

    for (int e = tid; e < 512; e += 256) {
        int p = e >> 4, d4 = e & 15;
        float4 s = *(const float4*)(src + ((start + p) * NKV + k) * DH + d4 * 4);
        float4 bp = *(const float4*)(block_pos + p * DH + d4 * 4);
        float4 r; r.x = s.x + bp.x; r.y = s.y + bp.y; r.z = s.z + bp.z; r.w = s.w + bp.w;
        *(float4*)&flat[(p >> 3) * 516 + (p & 7) * 64 + d4 * 4] = r;
    }
    __syncthreads();
    {
        int h = tid >> 2, part = tid & 3;
        const float* wr = w1 + h * 2048 + part * 512;
        const float* fl = flat + part * 516;
        float s = 0.0f;
        for (int j = 0; j < 512; j += 4) {
            float4 a = *(const float4*)(fl + j);
            float4 b = *(const float4*)(wr + j);
            s += a.x * b.x + a.y * b.y + a.z * b.z + a.w * b.w;
        }
        s += __shfl_xor(s, 1);
        s += __shfl_xor(s, 2);
        if (part == 0) hidden[h] = gelu_exact(s + b1[h]);
    }
    __syncthreads();
    {
        int dh = tid >> 2, part = tid & 3;
        const float* wr = w2 + dh * 64 + part * 16;
        float s = 0.0f;
        #pragma unroll
        for (int hh = 0; hh < 16; ++hh) s += hidden[part * 16 + hh] * wr[hh];
        s += __shfl_xor(s, 1);
        s += __shfl_xor(s, 2);
        if (part == 0) dst[(n * NKV + k) * DH + dh] = s + b2[dh];
    }
}

// ---------------------------------------------------------------------------
// Compressed branch + top-8 (f32, selection exact). 4-query tile: ksum/vsum
// staging amortized 4x, chunk-row reads reused across the 4 queries.
// Wave r does the top-8 for query index r (4 butterfly series in parallel).
// Writes out = g0*ocmp; flash atomically adds the other branches.
// grid (256, 4).
// ---------------------------------------------------------------------------
__global__ __launch_bounds__(256) void nsa_cmp(
    const float* __restrict__ q, const float* __restrict__ gates_lin,
    const float* __restrict__ ksum, const float* __restrict__ vsum,
    float* __restrict__ out, unsigned int* __restrict__ selmask_ws)
{
    const int t0 = blockIdx.x * T4, k = blockIdx.y;
    const int tid = threadIdx.x, lane = tid & 63, r = tid >> 6;

    __shared__ float q_s[REP][T4][DH];
    __shared__ float chunk[64][66];
    __shared__ float p_cmp_s[REP][T4][64];

    #pragma unroll
    for (int tt = 0; tt < T4; ++tt)
        q_s[r][tt][lane] = q[((r * NKV + k) * T_LEN + t0 + tt) * DH + lane];
    for (int e = tid; e < 64 * 32; e += 256) {
        int p = e >> 5, d2 = e & 31;
        int nn = (p < NB) ? p : NB - 1;
        *(float2*)&chunk[p][d2 * 2] = *(const float2*)(ksum + (nn * NKV + k) * DH + d2 * 2);
    }
    __syncthreads();

    // scores for 4 queries, reusing each chunk row read
    float sarr[T4];
    {
        float acc[T4] = {0.f, 0.f, 0.f, 0.f};
        #pragma unroll 8
        for (int d2 = 0; d2 < 32; ++d2) {
            float2 cd = *(const float2*)&chunk[lane][d2 * 2];
            #pragma unroll
            for (int tt = 0; tt < T4; ++tt) {
                float2 qd = *(const float2*)&q_s[r][tt][d2 * 2];
                acc[tt] += qd.x * cd.x + qd.y * cd.y;
            }
        }
        #pragma unroll
        for (int tt = 0; tt < T4; ++tt) {
            bool ok = (lane < NB) && ((lane * 16 + 31) <= (t0 + tt));
            sarr[tt] = ok ? acc[tt] * 0.125f : -1e30f;
        }
    }
    #pragma unroll
    for (int tt = 0; tt < T4; ++tt) {
        float m = sarr[tt];
        for (int off = 32; off; off >>= 1) m = fmaxf(m, __shfl_xor(m, off));
        float e = (lane < NB) ? expf(sarr[tt] - m) : 0.0f;
        float sum = e;
        for (int off = 32; off; off >>= 1) sum += __shfl_xor(sum, off);
        p_cmp_s[r][tt][lane] = (lane < NB) ? (e / sum) : 0.0f;
    }
    __syncthreads();

    // stage vsum (all threads); wave r runs top-8 for query t0+r in parallel
    for (int e2 = tid; e2 < 64 * 32; e2 += 256) {
        int p = e2 >> 5, d2 = e2 & 31;
        int nn = (p < NB) ? p : NB - 1;
        *(float2*)&chunk[p][d2 * 2] = *(const float2*)(vsum + (nn * NKV + k) * DH + d2 * 2);
    }
    {
        float imp = (lane < NB)
            ? (p_cmp_s[0][r][lane] + p_cmp_s[1][r][lane] + p_cmp_s[2][r][lane] + p_cmp_s[3][r][lane])
            : -1e30f;
        unsigned long long msk = 0ull;
        for (int it = 0; it < TOPN; ++it) {
            float v = imp; int i = lane;
            for (int off = 32; off; off >>= 1) {
                float ov = __shfl_xor(v, off);
                int   oi = __shfl_xor(i, off);
                if (ov > v || (ov == v && oi < i)) { v = ov; i = oi; }
            }
            msk |= 1ull << i;           // wave-uniform after butterfly
            if (lane == i) imp = -1e30f;
        }
        if (lane == 0) {
            selmask_ws[(k * T_LEN + t0 + r) * 2 + 0] = (unsigned int)(msk & 0xffffffffu);
            selmask_ws[(k * T_LEN + t0 + r) * 2 + 1] = (unsigned int)(msk >> 32);
        }
    }
    __syncthreads();

    float oc[T4] = {0.f, 0.f, 0.f, 0.f};
    #pragma unroll 4
    for (int n = 0; n < NB; ++n) {
        float cv = chunk[n][lane];
        #pragma unroll
        for (int tt = 0; tt < T4; ++tt)
            oc[tt] += p_cmp_s[r][tt][n] * cv;
    }
    const int hq = r * NKV + k;
    #pragma unroll
    for (int tt = 0; tt < T4; ++tt) {
        int t = t0 + tt;
        float o = (t >= 31) ? oc[tt] : 0.0f;     // vis.any
        float g0 = sigmoidf(gates_lin[t * 48 + hq * 3]);
        out[(hq * T_LEN + t) * DH + lane] = g0 * o;
    }
}

// ---------------------------------------------------------------------------
// Flash machinery — ONLINE single-sweep (r12): running-max rescale replaces
// the r10/r11 two-sweep (halves staging + QK MFMAs). sel: weight = membership
// count in {0,1,2} (block b covers p iff b ∈ {p>>4,(p>>4)-1}); chunk-skip
// bitmask visits only chunks touched by the tile's selected blocks.
// ---------------------------------------------------------------------------
template<bool SEL>
__device__ __forceinline__ float weightf(int p, int tq, unsigned mk0, unsigned mk1) {
    if (SEL) {
        int b = p >> 4;
        unsigned c = (b < 32) ? ((mk0 >> b) & 1u) : ((mk1 >> (b - 32)) & 1u);
        int b2 = b - 1;
        if (b2 >= 0)
            c += (b2 < 32) ? ((mk0 >> b2) & 1u) : ((mk1 >> (b2 - 32)) & 1u);
        return (p <= tq) ? (float)c : 0.0f;
    } else {
        return (p <= tq && p > tq - 256) ? 1.0f : 0.0f;
    }
}

__device__ __forceinline__ void stage_k_bf16(const float* kptr, int k, int cb, int tid,
                                             unsigned short (*ks)[72]) {
    int row = tid >> 2, dseg = tid & 3;
    const float* src = kptr + (((cb << 6) + row) * NKV + k) * DH + dseg * 16;
    float4 a0 = *(const float4*)(src);
    float4 a1 = *(const float4*)(src + 4);
    float4 a2 = *(const float4*)(src + 8);
    float4 a3 = *(const float4*)(src + 12);
    *(bf16x8*)&ks[row][dseg * 16]     = cvt8(a0, a1);
    *(bf16x8*)&ks[row][dseg * 16 + 8] = cvt8(a2, a3);
}

__device__ __forceinline__ void stage_v_t(const float* vptr, int k, int cb, int tid,
                                          unsigned short (*vt)[88]) {
    int l = tid & 63, wv = tid >> 6;
    int dbase = wv * 16 + ((l >> 5) << 3);    // 8 dims per thread
    int pp = (l & 31) * 2;                    // position pair
    const float* v0 = vptr + (((cb << 6) + pp) * NKV + k) * DH + dbase;
    const float* v1 = v0 + NKV * DH;
    float4 x0 = *(const float4*)v0, x1 = *(const float4*)(v0 + 4);
    float4 y0 = *(const float4*)v1, y1 = *(const float4*)(v1 + 4);
    union { __hip_bfloat162 v; unsigned u; } t_;
    t_.v = __float22bfloat162_rn(make_float2(x0.x, y0.x)); *(unsigned*)&vt[dbase + 0][pp] = t_.u;
    t_.v = __float22bfloat162_rn(make_float2(x0.y, y0.y)); *(unsigned*)&vt[dbase + 1][pp] = t_.u;
    t_.v = __float22bfloat162_rn(make_float2(x0.z, y0.z)); *(unsigned*)&vt[dbase + 2][pp] = t_.u;
    t_.v = __float22bfloat162_rn(make_float2(x0.w, y0.w)); *(unsigned*)&vt[dbase + 3][pp] = t_.u;
    t_.v = __float22bfloat162_rn(make_float2(x1.x, y1.x)); *(unsigned*)&vt[dbase + 4][pp] = t_.u;
    t_.v = __float22bfloat162_rn(make_float2(x1.y, y1.y)); *(unsigned*)&vt[dbase + 5][pp] = t_.u;
    t_.v = __float22bfloat162_rn(make_float2(x1.z, y1.z)); *(unsigned*)&vt[dbase + 6][pp] = t_.u;
    t_.v = __float22bfloat162_rn(make_float2(x1.w, y1.w)); *(unsigned*)&vt[dbase + 7][pp] = t_.u;
}

template<bool SEL>
__device__ __forceinline__ void flash_branch(
    const float* kptr, const float* vptr, int k, int t0, int c0, int c1,
    unsigned cmask,
    int tid, int quad, int col,
    bf16x8 qf0, bf16x8 qf1,
    unsigned short (*ks)[72], unsigned short (*vt)[88], float (*ps)[76],
    const unsigned int (*selm)[2],
    f32x4 (&O)[4])
{
    unsigned mk0[4] = {0,0,0,0}, mk1[4] = {0,0,0,0};
    int tq[4];
    #pragma unroll
    for (int g = 0; g < 4; ++g) {
        int row = quad * 4 + g;
        tq[g] = t0 + row;
        if (SEL) { mk0[g] = selm[row][0]; mk1[g] = selm[row][1]; }
    }

    float M[4] = {-1e30f, -1e30f, -1e30f, -1e30f};
    float l[4] = {0.f, 0.f, 0.f, 0.f};
    f32x4 z = {0.f, 0.f, 0.f, 0.f};
    O[0] = z; O[1] = z; O[2] = z; O[3] = z;

    for (int cb = c0; cb <= c1; ++cb) {
        if (!((cmask >> cb) & 1u)) continue;   // block-uniform branch
        __syncthreads();
        stage_k_bf16(kptr, k, cb, tid, ks);
        stage_v_t(vptr, k, cb, tid, vt);
        __syncthreads();

        // QK^T scores for this chunk
        float sv[4][4];
        #pragma unroll
        for (int nt = 0; nt < 4; ++nt) {
            bf16x8 b0 = *(const bf16x8*)&ks[nt * 16 + col][quad * 8];
            bf16x8 b1 = *(const bf16x8*)&ks[nt * 16 + col][32 + quad * 8];
            f32x4 sc = {0.f, 0.f, 0.f, 0.f};
            sc = __builtin_amdgcn_mfma_f32_16x16x32_bf16(qf0, b0, sc, 0, 0, 0);
            sc = __builtin_amdgcn_mfma_f32_16x16x32_bf16(qf1, b1, sc, 0, 0, 0);
            #pragma unroll
            for (int g = 0; g < 4; ++g) sv[nt][g] = sc[g] * 0.125f;
        }
        // online max update + rescale of O, l
        #pragma unroll
        for (int g = 0; g < 4; ++g) {
            float cm = -1e30f;
            #pragma unroll
            for (int nt = 0; nt < 4; ++nt) {
                int p = (cb << 6) + nt * 16 + col;
                float w = weightf<SEL>(p, tq[g], mk0[g], mk1[g]);
                if (w > 0.0f) cm = fmaxf(cm, sv[nt][g]);
            }
            cm = fmaxf(cm, __shfl_xor(cm, 1));
            cm = fmaxf(cm, __shfl_xor(cm, 2));
            cm = fmaxf(cm, __shfl_xor(cm, 4));
            cm = fmaxf(cm, __shfl_xor(cm, 8));
            float nM = fmaxf(M[g], cm);
            float sc_ = expf(M[g] - nM);       // ==1 when unchanged; ==0 from -1e30
            l[g] *= sc_;
            M[g] = nM;
            #pragma unroll
            for (int nt = 0; nt < 4; ++nt) O[nt][g] *= sc_;
        }
        // exp weights -> ps (per-wave), partial l
        #pragma unroll
        for (int nt = 0; nt < 4; ++nt) {
            #pragma unroll
            for (int g = 0; g < 4; ++g) {
                int p = (cb << 6) + nt * 16 + col;
                float w = weightf<SEL>(p, tq[g], mk0[g], mk1[g]);
                float ev = (w > 0.0f) ? w * expf(sv[nt][g] - M[g]) : 0.0f;
                l[g] += ev;
                ps[quad * 4 + g][nt * 16 + col] = ev;
            }
        }
        // P·V
        float4 p0 = *(const float4*)&ps[col][quad * 8];
        float4 p1 = *(const float4*)&ps[col][quad * 8 + 4];
        float4 p2 = *(const float4*)&ps[col][32 + quad * 8];
        float4 p3 = *(const float4*)&ps[col][32 + quad * 8 + 4];
        bf16x8 ap0 = cvt8(p0, p1);
        bf16x8 ap1 = cvt8(p2, p3);
        #pragma unroll
        for (int nt = 0; nt < 4; ++nt) {
            bf16x8 bv0 = *(const bf16x8*)&vt[nt * 16 + col][quad * 8];
            bf16x8 bv1 = *(const bf16x8*)&vt[nt * 16 + col][32 + quad * 8];
            O[nt] = __builtin_amdgcn_mfma_f32_16x16x32_bf16(ap0, bv0, O[nt], 0, 0, 0);
            O[nt] = __builtin_amdgcn_mfma_f32_16x16x32_bf16(ap1, bv1, O[nt], 0, 0, 0);
        }
    }
    #pragma unroll
    for (int g = 0; g < 4; ++g) {
        l[g] += __shfl_xor(l[g], 1);
        l[g] += __shfl_xor(l[g], 2);
        l[g] += __shfl_xor(l[g], 4);
        l[g] += __shfl_xor(l[g], 8);
        float inv = 1.0f / l[g];
        #pragma unroll
        for (int nt = 0; nt < 4; ++nt) O[nt][g] *= inv;
    }
}

// ---------------------------------------------------------------------------
// Flash kernel: grid (64, 4, 2); z = branch (0=sel, 1=win). Online softmax;
// sel visits only chunks in the tile's union chunk-bitmask. atomicAdd onto
// out (= g0*ocmp from nsa_cmp, stream-ordered).
// ---------------------------------------------------------------------------
__global__ __launch_bounds__(256) void nsa_flash(
    const float* __restrict__ q, const float* __restrict__ gates_lin,
    const float* __restrict__ k_slc, const float* __restrict__ v_slc,
    const float* __restrict__ k_win, const float* __restrict__ v_win,
    const unsigned int* __restrict__ selmask_ws,
    float* __restrict__ out)
{
    const int t0 = blockIdx.x * TQ;
    const int k  = blockIdx.y;
    const int br = blockIdx.z;          // 0 = selected, 1 = window
    const int tid = threadIdx.x, lane = tid & 63, r = tid >> 6;
    const int quad = lane >> 4, col = lane & 15;

    __shared__ unsigned short qs[REP][TQ][72];
    __shared__ unsigned short ks[64][72];
    __shared__ unsigned short vt[64][88];
    __shared__ float ps[REP][TQ][76];
    __shared__ unsigned int selm[TQ][2];
    __shared__ unsigned int chunkmask_s;

    // stage Q (bf16): each wave stages its own rep
    {
        int qrow = lane >> 2, dseg = lane & 3;
        const float* src = q + ((r * NKV + k) * T_LEN + t0 + qrow) * DH + dseg * 16;
        float4 a0 = *(const float4*)src,       a1 = *(const float4*)(src + 4);
        float4 a2 = *(const float4*)(src + 8), a3 = *(const float4*)(src + 12);
        *(bf16x8*)&qs[r][qrow][dseg * 16]     = cvt8(a0, a1);
        *(bf16x8*)&qs[r][qrow][dseg * 16 + 8] = cvt8(a2, a3);
    }
    if (tid < TQ) {
        selm[tid][0] = selmask_ws[(k * T_LEN + t0 + tid) * 2 + 0];
        selm[tid][1] = selmask_ws[(k * T_LEN + t0 + tid) * 2 + 1];
    }
    __syncthreads();

    // sel: union chunk bitmask over the 16 queries. Block b covers chunks
    // b>>2 and b>>2+1 (latter iff (b&3)==3). Bit 63 provably never set.
    if (br == 0 && tid < TQ) {
        unsigned long long mk = (unsigned long long)selm[tid][0]
                              | ((unsigned long long)selm[tid][1] << 32);
        unsigned cm = 0;
        #pragma unroll
        for (int m2 = 0; m2 < 16; ++m2) {
            unsigned nib = (unsigned)((mk >> (4 * m2)) & 0xFull);
            if (nib) cm |= 1u << m2;
            if (nib & 8u) cm |= 1u << (m2 + 1);
        }
        // OR-reduce over 16 active lanes (partners all within 0..15 — EXEC-safe)
        cm |= __shfl_xor(cm, 1); cm |= __shfl_xor(cm, 2);
        cm |= __shfl_xor(cm, 4); cm |= __shfl_xor(cm, 8);
        if (tid == 0) chunkmask_s = cm;
    }
    __syncthreads();

    bf16x8 qf0 = *(const bf16x8*)&qs[r][col][quad * 8];
    bf16x8 qf1 = *(const bf16x8*)&qs[r][col][32 + quad * 8];

    const int tmax = t0 + TQ - 1;
    f32x4 O[4];
    if (br == 0) {
        flash_branch<true>(k_slc, v_slc, k, t0, 0, tmax >> 6, chunkmask_s,
                           tid, quad, col, qf0, qf1, ks, vt, ps[r], selm, O);
    } else {
        int wlo = t0 - 255; if (wlo < 0) wlo = 0;
        flash_branch<false>(k_win, v_win, k, t0, wlo >> 6, tmax >> 6, 0xFFFFFFFFu,
                            tid, quad, col, qf0, qf1, ks, vt, ps[r], selm, O);
    }

    // gated atomic accumulate (out already holds g0*ocmp)
    const int hq = r * NKV + k;
    #pragma unroll
    for (int g = 0; g < 4; ++g) {
        int tq = t0 + quad * 4 + g;
        float gg = sigmoidf(gates_lin[tq * 48 + hq * 3 + 1 + br]);
        #pragma unroll
        for (int nt = 0; nt < 4; ++nt) {
            int d = nt * 16 + col;
            atomicAdd(&out[(hq * T_LEN + tq) * DH + d], gg * O[nt][g]);
        }
    }
}

extern "C" void kernel_launch(void* const* d_in, const int* in_sizes, int n_in,
                              void* d_out, int out_size, void* d_ws, size_t ws_size,
                              hipStream_t stream) {
    const float* x         = (const float*)d_in[0];
    const float* q         = (const float*)d_in[1];
    const float* gate_w    = (const float*)d_in[2];
    const float* gate_b    = (const float*)d_in[3];
    const float* wk_cmp    = (const float*)d_in[4];
    const float* wv_cmp    = (const float*)d_in[5];
    const float* wk_slc    = (const float*)d_in[6];
    const float* wv_slc    = (const float*)d_in[7];
    const float* wk_win    = (const float*)d_in[8];
    const float* wv_win    = (const float*)d_in[9];
    const float* block_pos = (const float*)d_in[10];
    const float* ck1_w     = (const float*)d_in[11];
    const float* ck1_b     = (const float*)d_in[12];
    const float* ck2_w     = (const float*)d_in[13];
    const float* ck2_b     = (const float*)d_in[14];
    const float* cv1_w     = (const float*)d_in[15];
    const float* cv1_b     = (const float*)d_in[16];
    const float* cv2_w     = (const float*)d_in[17];
    const float* cv2_b     = (const float*)d_in[18];
    float* out = (float*)d_out;

    float* ws = (float*)d_ws;
    float* gates_lin = ws;                         // 1024*48
    float* k_cmp = gates_lin + T_LEN * 48;         // 1024*256 each
    float* v_cmp = k_cmp + T_LEN * KVD;
    float* k_slc = v_cmp + T_LEN * KVD;
    float* v_slc = k_slc + T_LEN * KVD;
    float* k_win = v_slc + T_LEN * KVD;
    float* v_win = k_win + T_LEN * KVD;
    float* ksum  = v_win + T_LEN * KVD;            // 63*4*64 each
    float* vsum  = ksum + NB * KVD;
    unsigned int* selmask_ws = (unsigned int*)(vsum + NB * KVD); // 4*1024*2

    dim3 blk(256);
    size_t smem_bytes = 2 * 32 * 68 * sizeof(float);
    proj_all<<<dim3(25, 16), blk, smem_bytes, stream>>>(
        x, gate_w, gate_b, wk_cmp, wv_cmp, wk_slc, wv_slc, wk_win, wv_win,
        gates_lin, k_cmp, v_cmp, k_slc, v_slc, k_win, v_win);
    nsa_summarize<<<dim3(NB, NKV, 2), blk, 0, stream>>>(
        k_cmp, v_cmp, block_pos,
        ck1_w, ck1_b, ck2_w, ck2_b, cv1_w, cv1_b, cv2_w, cv2_b,
        ksum, vsum);
    nsa_cmp<<<dim3(T_LEN / T4, NKV), blk, 0, stream>>>(
        q, gates_lin, ksum, vsum, out, selmask_ws);
    nsa_flash<<<dim3(T_LEN / TQ, NKV, 2), blk, 0, stream>>>(
        q, gates_lin, k_slc, v_slc, k_win, v_win, selmask_ws, out);
}

// Round 13
// 229.053 us; speedup vs baseline: 18.8393x; 1.1049x over previous
//
#include <hip/hip_runtime.h>
#include <hip/hip_bf16.h>
#include <math.h>

#define T_LEN 1024
#define D_MODEL 1024
#define NKV 4
#define REP 4
#define DH 64
#define NB 63
#define TOPN 8
#define KVD 256        // NKV*DH
#define LDIM2 1328     // virtual concatenated width without k_cmp
#define TQ 16          // query tile for flash kernel
#define T4 4           // query tile for cmp kernel
#define SGN 4          // n-group for summarize

typedef __attribute__((ext_vector_type(8))) short bf16x8;
typedef __attribute__((ext_vector_type(4))) float f32x4;

__device__ __forceinline__ float gelu_exact(float x) {
    return 0.5f * x * (1.0f + erff(x * 0.70710678118654752f));
}
__device__ __forceinline__ float sigmoidf(float x) {
    return 1.0f / (1.0f + expf(-x));
}
// pack 8 f32 -> 8 bf16 via HW v_cvt_pk_bf16_f32 (RNE)
__device__ __forceinline__ bf16x8 cvt8(float4 a0, float4 a1) {
    union { __hip_bfloat162 v; short2 s; } u0, u1, u2, u3;
    u0.v = __float22bfloat162_rn(make_float2(a0.x, a0.y));
    u1.v = __float22bfloat162_rn(make_float2(a0.z, a0.w));
    u2.v = __float22bfloat162_rn(make_float2(a1.x, a1.y));
    u3.v = __float22bfloat162_rn(make_float2(a1.z, a1.w));
    bf16x8 r;
    r[0] = u0.s.x; r[1] = u0.s.y; r[2] = u1.s.x; r[3] = u1.s.y;
    r[4] = u2.s.x; r[5] = u2.s.y; r[6] = u3.s.x; r[7] = u3.s.y;
    return r;
}

// ---------------------------------------------------------------------------
// Merged projection dispatch, grid (25,16), dynamic LDS 17408 B.
// r13: register-prefetch pipelining — next k-step's global loads issue after
// the staging barrier and drain during the MFMA/FMA work (lgkm-gated), so the
// vmcnt wait lands at the NEXT iteration's LDS write instead of stalling.
// ---------------------------------------------------------------------------
__global__ __launch_bounds__(256) void proj_all(
    const float* __restrict__ x,
    const float* __restrict__ gate_w, const float* __restrict__ gate_b,
    const float* __restrict__ wk_cmp, const float* __restrict__ wv_cmp,
    const float* __restrict__ wk_slc, const float* __restrict__ wv_slc,
    const float* __restrict__ wk_win, const float* __restrict__ wv_win,
    float* __restrict__ gates_lin, float* __restrict__ k_cmp,
    float* __restrict__ v_cmp,
    float* __restrict__ k_slc, float* __restrict__ v_slc,
    float* __restrict__ k_win, float* __restrict__ v_win)
{
    extern __shared__ char smem[];
    const int tid = threadIdx.x;
    const int m0 = blockIdx.y * 64;

    if (blockIdx.x < 21) {
        typedef unsigned short row40[40];
        row40* As = (row40*)smem;
        row40* Bs = (row40*)(smem + 64 * 40 * sizeof(unsigned short));
        const int lane = tid & 63;
        const int w = tid >> 6;
        const int n0 = blockIdx.x * 64;

        const int srow = tid >> 2;
        const int sseg = tid & 3;
        const float* ga = x + (m0 + srow) * D_MODEL + sseg * 8;
        const float* gb;
        {
            int nn = n0 + srow;
            if (nn < 48)        gb = gate_w + nn * D_MODEL;
            else if (nn < 304)  gb = wv_cmp + (nn - 48) * D_MODEL;
            else if (nn < 560)  gb = wk_slc + (nn - 304) * D_MODEL;
            else if (nn < 816)  gb = wv_slc + (nn - 560) * D_MODEL;
            else if (nn < 1072) gb = wk_win + (nn - 816) * D_MODEL;
            else if (nn < 1328) gb = wv_win + (nn - 1072) * D_MODEL;
            else                gb = gate_w;
            gb += sseg * 8;
        }

        f32x4 acc[4] = {};
        const int arow = (w << 4) + (lane & 15);
        const int kk8  = (lane >> 4) * 8;

        // prefetch k0 = 0
        float4 a0 = *(const float4*)(ga);
        float4 a1 = *(const float4*)(ga + 4);
        float4 b0 = *(const float4*)(gb);
        float4 b1 = *(const float4*)(gb + 4);

        for (int k0 = 0; k0 < D_MODEL; k0 += 32) {
            bf16x8 ap = cvt8(a0, a1);
            bf16x8 bp = cvt8(b0, b1);
            __syncthreads();
            *(bf16x8*)&As[srow][sseg * 8] = ap;
            *(bf16x8*)&Bs[srow][sseg * 8] = bp;
            __syncthreads();
            if (k0 + 32 < D_MODEL) {          // issue next loads; no wait here
                a0 = *(const float4*)(ga + k0 + 32);
                a1 = *(const float4*)(ga + k0 + 36);
                b0 = *(const float4*)(gb + k0 + 32);
                b1 = *(const float4*)(gb + k0 + 36);
            }
            bf16x8 af = *(bf16x8*)&As[arow][kk8];
            #pragma unroll
            for (int j = 0; j < 4; ++j) {
                bf16x8 bfr = *(bf16x8*)&Bs[j * 16 + (lane & 15)][kk8];
                acc[j] = __builtin_amdgcn_mfma_f32_16x16x32_bf16(af, bfr, acc[j], 0, 0, 0);
            }
        }

        #pragma unroll
        for (int j = 0; j < 4; ++j) {
            int col = n0 + j * 16 + (lane & 15);
            if (col >= LDIM2) continue;
            int rbase = m0 + (w << 4) + (lane >> 4) * 4;
            float* dst; int cc; int stride = 256; float badd = 0.0f;
            if (col < 48)        { dst = gates_lin; cc = col;        stride = 48; badd = gate_b[col]; }
            else if (col < 304)  { dst = v_cmp;     cc = col - 48;   }
            else if (col < 560)  { dst = k_slc;     cc = col - 304;  }
            else if (col < 816)  { dst = v_slc;     cc = col - 560;  }
            else if (col < 1072) { dst = k_win;     cc = col - 816;  }
            else                 { dst = v_win;     cc = col - 1072; }
            #pragma unroll
            for (int rg = 0; rg < 4; ++rg)
                dst[(rbase + rg) * stride + cc] = acc[j][rg] + badd;
        }
    } else {
        typedef float row68[68];
        row68* As = (row68*)smem;
        row68* Bs = (row68*)(smem + 32 * 68 * sizeof(float));
        const int tx = tid & 15, ty = tid >> 4;
        const int n0 = (blockIdx.x - 21) * 64;
        const int srow = tid >> 2, sseg = tid & 3;
        const float* ga = x + (m0 + srow) * D_MODEL + sseg * 8;
        const float* gb = wk_cmp + (n0 + srow) * D_MODEL + sseg * 8;

        float acc[4][4] = {};
        float4 a0 = *(const float4*)(ga);
        float4 a1 = *(const float4*)(ga + 4);
        float4 b0 = *(const float4*)(gb);
        float4 b1 = *(const float4*)(gb + 4);

        for (int k0 = 0; k0 < D_MODEL; k0 += 32) {
            __syncthreads();
            As[sseg*8+0][srow]=a0.x; As[sseg*8+1][srow]=a0.y; As[sseg*8+2][srow]=a0.z; As[sseg*8+3][srow]=a0.w;
            As[sseg*8+4][srow]=a1.x; As[sseg*8+5][srow]=a1.y; As[sseg*8+6][srow]=a1.z; As[sseg*8+7][srow]=a1.w;
            Bs[sseg*8+0][srow]=b0.x; Bs[sseg*8+1][srow]=b0.y; Bs[sseg*8+2][srow]=b0.z; Bs[sseg*8+3][srow]=b0.w;
            Bs[sseg*8+4][srow]=b1.x; Bs[sseg*8+5][srow]=b1.y; Bs[sseg*8+6][srow]=b1.z; Bs[sseg*8+7][srow]=b1.w;
            __syncthreads();
            if (k0 + 32 < D_MODEL) {
                a0 = *(const float4*)(ga + k0 + 32);
                a1 = *(const float4*)(ga + k0 + 36);
                b0 = *(const float4*)(gb + k0 + 32);
                b1 = *(const float4*)(gb + k0 + 36);
            }
            #pragma unroll
            for (int kk = 0; kk < 32; ++kk) {
                float4 a4 = *(const float4*)&As[kk][ty * 4];
                float4 b4 = *(const float4*)&Bs[kk][tx * 4];
                acc[0][0] += a4.x*b4.x; acc[0][1] += a4.x*b4.y; acc[0][2] += a4.x*b4.z; acc[0][3] += a4.x*b4.w;
                acc[1][0] += a4.y*b4.x; acc[1][1] += a4.y*b4.y; acc[1][2] += a4.y*b4.z; acc[1][3] += a4.y*b4.w;
                acc[2][0] += a4.z*b4.x; acc[2][1] += a4.z*b4.y; acc[2][2] += a4.z*b4.z; acc[2][3] += a4.z*b4.w;
                acc[3][0] += a4.w*b4.x; acc[3][1] += a4.w*b4.y; acc[3][2] += a4.w*b4.z; acc[3][3] += a4.w*b4.w;
            }
        }
        #pragma unroll
        for (int i = 0; i < 4; ++i) {
            int mm = m0 + ty * 4 + i;
            #pragma unroll
            for (int j = 0; j < 4; ++j)
                k_cmp[mm * KVD + n0 + tx * 4 + j] = acc[i][j];
        }
    }
}

// ---------------------------------------------------------------------------
// Block summaries, r13: 4-wide n-tiling. grid (16, 4, 2). Each block computes
// SGN=4 consecutive n with ONE pass over w1/w2 (r12 read the full 512 KB w1
// once per (n,k,which) = 258 MB of L2 traffic; now 64 MB). Dot order per n
// unchanged -> bit-identical results.
// ---------------------------------------------------------------------------
__global__ __launch_bounds__(256) void nsa_summarize(
    const float* __restrict__ k_cmp, const float* __restrict__ v_cmp,
    const float* __restrict__ block_pos,
    const float* __restrict__ ck1_w, const float* __restrict__ ck1_b,
    const float* __restrict__ ck2_w, const float* __restrict__ ck2_b,
    const float* __restrict__ cv1_w, const float* __restrict__ cv1_b,
    const float* __restrict__ cv2_w, const float* __restrict__ cv2_b,
    float* __restrict__ ksum, float* __restrict__ vsum)
{
    const int ng = blockIdx.x, k = blockIdx.y, which = blockIdx.z;
    const int n0 = ng * SGN;
    const float* src = which ? v_cmp : k_cmp;
    const float* w1  = which ? cv1_w : ck1_w;
    const float* b1  = which ? cv1_b : ck1_b;
    const float* w2  = which ? cv2_w : ck2_w;
    const float* b2  = which ? cv2_b : ck2_b;
    float* dst       = which ? vsum  : ksum;

    __shared__ float flat[SGN][4 * 516];
    __shared__ float hidden[SGN][DH];
    const int tid = threadIdx.x;

    #pragma unroll
    for (int j = 0; j < SGN; ++j) {
        int n = n0 + j; if (n >= NB) n = NB - 1;   // clamp (writes guarded)
        int start = n * 16;
        for (int e = tid; e < 512; e += 256) {
            int p = e >> 4, d4 = e & 15;
            float4 s = *(const float4*)(src + ((start + p) * NKV + k) * DH + d4 * 4);
            float4 bp = *(const float4*)(block_pos + p * DH + d4 * 4);
            float4 r; r.x = s.x + bp.x; r.y = s.y + bp.y; r.z = s.z + bp.z; r.w = s.w + bp.w;
            *(float4*)&flat[j][(p >> 3) * 516 + (p & 7) * 64 + d4 * 4] = r;
        }
    }
    __syncthreads();
    {
        int h = tid >> 2, part = tid & 3;
        const float* wr = w1 + h * 2048 + part * 512;
        float s[SGN] = {0.f, 0.f, 0.f, 0.f};
        for (int jj = 0; jj < 512; jj += 4) {
            float4 b = *(const float4*)(wr + jj);
            #pragma unroll
            for (int j = 0; j < SGN; ++j) {
                float4 a = *(const float4*)&flat[j][part * 516 + jj];
                s[j] += a.x * b.x + a.y * b.y + a.z * b.z + a.w * b.w;
            }
        }
        #pragma unroll
        for (int j = 0; j < SGN; ++j) {
            float v = s[j];
            v += __shfl_xor(v, 1);
            v += __shfl_xor(v, 2);
            if (part == 0) hidden[j][h] = gelu_exact(v + b1[h]);
        }
    }
    __syncthreads();
    {
        int dh = tid >> 2, part = tid & 3;
        const float* wr = w2 + dh * 64 + part * 16;
        float s[SGN] = {0.f, 0.f, 0.f, 0.f};
        #pragma unroll
        for (int hh = 0; hh < 16; ++hh) {
            float b = wr[hh];
            #pragma unroll
            for (int j = 0; j < SGN; ++j)
                s[j] += hidden[j][part * 16 + hh] * b;
        }
        #pragma unroll
        for (int j = 0; j < SGN; ++j) {
            float v = s[j];
            v += __shfl_xor(v, 1);
            v += __shfl_xor(v, 2);
            if (part == 0 && (n0 + j) < NB)
                dst[((n0 + j) * NKV + k) * DH + dh] = v + b2[dh];
        }
    }
}

// ---------------------------------------------------------------------------
// Compressed branch + top-8 (f32, selection exact). Unchanged from r12.
// grid (256, 4).
// ---------------------------------------------------------------------------
__global__ __launch_bounds__(256) void nsa_cmp(
    const float* __restrict__ q, const float* __restrict__ gates_lin,
    const float* __restrict__ ksum, const float* __restrict__ vsum,
    float* __restrict__ out, unsigned int* __restrict__ selmask_ws)
{
    const int t0 = blockIdx.x * T4, k = blockIdx.y;
    const int tid = threadIdx.x, lane = tid & 63, r = tid >> 6;

    __shared__ float q_s[REP][T4][DH];
    __shared__ float chunk[64][66];
    __shared__ float p_cmp_s[REP][T4][64];

    #pragma unroll
    for (int tt = 0; tt < T4; ++tt)
        q_s[r][tt][lane] = q[((r * NKV + k) * T_LEN + t0 + tt) * DH + lane];
    for (int e = tid; e < 64 * 32; e += 256) {
        int p = e >> 5, d2 = e & 31;
        int nn = (p < NB) ? p : NB - 1;
        *(float2*)&chunk[p][d2 * 2] = *(const float2*)(ksum + (nn * NKV + k) * DH + d2 * 2);
    }
    __syncthreads();

    float sarr[T4];
    {
        float acc[T4] = {0.f, 0.f, 0.f, 0.f};
        #pragma unroll 8
        for (int d2 = 0; d2 < 32; ++d2) {
            float2 cd = *(const float2*)&chunk[lane][d2 * 2];
            #pragma unroll
            for (int tt = 0; tt < T4; ++tt) {
                float2 qd = *(const float2*)&q_s[r][tt][d2 * 2];
                acc[tt] += qd.x * cd.x + qd.y * cd.y;
            }
        }
        #pragma unroll
        for (int tt = 0; tt < T4; ++tt) {
            bool ok = (lane < NB) && ((lane * 16 + 31) <= (t0 + tt));
            sarr[tt] = ok ? acc[tt] * 0.125f : -1e30f;
        }
    }
    #pragma unroll
    for (int tt = 0; tt < T4; ++tt) {
        float m = sarr[tt];
        for (int off = 32; off; off >>= 1) m = fmaxf(m, __shfl_xor(m, off));
        float e = (lane < NB) ? expf(sarr[tt] - m) : 0.0f;
        float sum = e;
        for (int off = 32; off; off >>= 1) sum += __shfl_xor(sum, off);
        p_cmp_s[r][tt][lane] = (lane < NB) ? (e / sum) : 0.0f;
    }
    __syncthreads();

    for (int e2 = tid; e2 < 64 * 32; e2 += 256) {
        int p = e2 >> 5, d2 = e2 & 31;
        int nn = (p < NB) ? p : NB - 1;
        *(float2*)&chunk[p][d2 * 2] = *(const float2*)(vsum + (nn * NKV + k) * DH + d2 * 2);
    }
    {
        float imp = (lane < NB)
            ? (p_cmp_s[0][r][lane] + p_cmp_s[1][r][lane] + p_cmp_s[2][r][lane] + p_cmp_s[3][r][lane])
            : -1e30f;
        unsigned long long msk = 0ull;
        for (int it = 0; it < TOPN; ++it) {
            float v = imp; int i = lane;
            for (int off = 32; off; off >>= 1) {
                float ov = __shfl_xor(v, off);
                int   oi = __shfl_xor(i, off);
                if (ov > v || (ov == v && oi < i)) { v = ov; i = oi; }
            }
            msk |= 1ull << i;
            if (lane == i) imp = -1e30f;
        }
        if (lane == 0) {
            selmask_ws[(k * T_LEN + t0 + r) * 2 + 0] = (unsigned int)(msk & 0xffffffffu);
            selmask_ws[(k * T_LEN + t0 + r) * 2 + 1] = (unsigned int)(msk >> 32);
        }
    }
    __syncthreads();

    float oc[T4] = {0.f, 0.f, 0.f, 0.f};
    #pragma unroll 4
    for (int n = 0; n < NB; ++n) {
        float cv = chunk[n][lane];
        #pragma unroll
        for (int tt = 0; tt < T4; ++tt)
            oc[tt] += p_cmp_s[r][tt][n] * cv;
    }
    const int hq = r * NKV + k;
    #pragma unroll
    for (int tt = 0; tt < T4; ++tt) {
        int t = t0 + tt;
        float o = (t >= 31) ? oc[tt] : 0.0f;
        float g0 = sigmoidf(gates_lin[t * 48 + hq * 3]);
        out[(hq * T_LEN + t) * DH + lane] = g0 * o;
    }
}

// ---------------------------------------------------------------------------
// Flash machinery — r13: register-prefetch pipelining on the chunk walk.
// Chunk iteration is a uniform bitmask walk (ctz on block-uniform mask —
// NO indexed private array, which would spill to scratch per r2/r3).
// Compute body identical to r12 (online softmax, count weights).
// ---------------------------------------------------------------------------
template<bool SEL>
__device__ __forceinline__ float weightf(int p, int tq, unsigned mk0, unsigned mk1) {
    if (SEL) {
        int b = p >> 4;
        unsigned c = (b < 32) ? ((mk0 >> b) & 1u) : ((mk1 >> (b - 32)) & 1u);
        int b2 = b - 1;
        if (b2 >= 0)
            c += (b2 < 32) ? ((mk0 >> b2) & 1u) : ((mk1 >> (b2 - 32)) & 1u);
        return (p <= tq) ? (float)c : 0.0f;
    } else {
        return (p <= tq && p > tq - 256) ? 1.0f : 0.0f;
    }
}

struct KRegs { float4 a0, a1, a2, a3; };
struct VRegs { float4 x0, x1, y0, y1; };

__device__ __forceinline__ KRegs load_k_regs(const float* kptr, int k, int cb, int tid) {
    int row = tid >> 2, dseg = tid & 3;
    const float* src = kptr + (((cb << 6) + row) * NKV + k) * DH + dseg * 16;
    KRegs r;
    r.a0 = *(const float4*)(src);
    r.a1 = *(const float4*)(src + 4);
    r.a2 = *(const float4*)(src + 8);
    r.a3 = *(const float4*)(src + 12);
    return r;
}
__device__ __forceinline__ void write_k(const KRegs& r, int tid, unsigned short (*ks)[72]) {
    int row = tid >> 2, dseg = tid & 3;
    *(bf16x8*)&ks[row][dseg * 16]     = cvt8(r.a0, r.a1);
    *(bf16x8*)&ks[row][dseg * 16 + 8] = cvt8(r.a2, r.a3);
}
__device__ __forceinline__ VRegs load_v_regs(const float* vptr, int k, int cb, int tid) {
    int l = tid & 63, wv = tid >> 6;
    int dbase = wv * 16 + ((l >> 5) << 3);
    int pp = (l & 31) * 2;
    const float* v0 = vptr + (((cb << 6) + pp) * NKV + k) * DH + dbase;
    const float* v1 = v0 + NKV * DH;
    VRegs r;
    r.x0 = *(const float4*)v0; r.x1 = *(const float4*)(v0 + 4);
    r.y0 = *(const float4*)v1; r.y1 = *(const float4*)(v1 + 4);
    return r;
}
__device__ __forceinline__ void write_v(const VRegs& r, int tid, unsigned short (*vt)[88]) {
    int l = tid & 63, wv = tid >> 6;
    int dbase = wv * 16 + ((l >> 5) << 3);
    int pp = (l & 31) * 2;
    union { __hip_bfloat162 v; unsigned u; } t_;
    t_.v = __float22bfloat162_rn(make_float2(r.x0.x, r.y0.x)); *(unsigned*)&vt[dbase + 0][pp] = t_.u;
    t_.v = __float22bfloat162_rn(make_float2(r.x0.y, r.y0.y)); *(unsigned*)&vt[dbase + 1][pp] = t_.u;
    t_.v = __float22bfloat162_rn(make_float2(r.x0.z, r.y0.z)); *(unsigned*)&vt[dbase + 2][pp] = t_.u;
    t_.v = __float22bfloat162_rn(make_float2(r.x0.w, r.y0.w)); *(unsigned*)&vt[dbase + 3][pp] = t_.u;
    t_.v = __float22bfloat162_rn(make_float2(r.x1.x, r.y1.x)); *(unsigned*)&vt[dbase + 4][pp] = t_.u;
    t_.v = __float22bfloat162_rn(make_float2(r.x1.y, r.y1.y)); *(unsigned*)&vt[dbase + 5][pp] = t_.u;
    t_.v = __float22bfloat162_rn(make_float2(r.x1.z, r.y1.z)); *(unsigned*)&vt[dbase + 6][pp] = t_.u;
    t_.v = __float22bfloat162_rn(make_float2(r.x1.w, r.y1.w)); *(unsigned*)&vt[dbase + 7][pp] = t_.u;
}

template<bool SEL>
__device__ __forceinline__ void flash_branch(
    const float* kptr, const float* vptr, int k, int t0, int c0, int c1,
    unsigned cmask,
    int tid, int quad, int col,
    bf16x8 qf0, bf16x8 qf1,
    unsigned short (*ks)[72], unsigned short (*vt)[88], float (*ps)[76],
    const unsigned int (*selm)[2],
    f32x4 (&O)[4])
{
    unsigned mk0[4] = {0,0,0,0}, mk1[4] = {0,0,0,0};
    int tq[4];
    #pragma unroll
    for (int g = 0; g < 4; ++g) {
        int row = quad * 4 + g;
        tq[g] = t0 + row;
        if (SEL) { mk0[g] = selm[row][0]; mk1[g] = selm[row][1]; }
    }

    float M[4] = {-1e30f, -1e30f, -1e30f, -1e30f};
    float l[4] = {0.f, 0.f, 0.f, 0.f};
    f32x4 z = {0.f, 0.f, 0.f, 0.f};
    O[0] = z; O[1] = z; O[2] = z; O[3] = z;

    // uniform chunk mask restricted to [c0, c1]
    unsigned rem = cmask & ((2u << c1) - 1u);   // c1 <= 15 always
    rem = (rem >> c0) << c0;

    if (rem) {
        int cb = __builtin_ctz(rem);
        KRegs kr = load_k_regs(kptr, k, cb, tid);
        VRegs vr = load_v_regs(vptr, k, cb, tid);
        while (true) {
            unsigned rem2 = rem & (rem - 1);
            int nxt = rem2 ? __builtin_ctz(rem2) : -1;
            __syncthreads();                       // prev round's LDS reads done
            write_k(kr, tid, ks);                  // vmcnt wait lands here
            write_v(vr, tid, vt);
            __syncthreads();
            if (nxt >= 0) {                        // issue next loads; no wait
                kr = load_k_regs(kptr, k, nxt, tid);
                vr = load_v_regs(vptr, k, nxt, tid);
            }

            // ---- compute on chunk cb (identical to r12) ----
            float sv[4][4];
            #pragma unroll
            for (int nt = 0; nt < 4; ++nt) {
                bf16x8 b0 = *(const bf16x8*)&ks[nt * 16 + col][quad * 8];
                bf16x8 b1 = *(const bf16x8*)&ks[nt * 16 + col][32 + quad * 8];
                f32x4 sc = {0.f, 0.f, 0.f, 0.f};
                sc = __builtin_amdgcn_mfma_f32_16x16x32_bf16(qf0, b0, sc, 0, 0, 0);
                sc = __builtin_amdgcn_mfma_f32_16x16x32_bf16(qf1, b1, sc, 0, 0, 0);
                #pragma unroll
                for (int g = 0; g < 4; ++g) sv[nt][g] = sc[g] * 0.125f;
            }
            #pragma unroll
            for (int g = 0; g < 4; ++g) {
                float cm = -1e30f;
                #pragma unroll
                for (int nt = 0; nt < 4; ++nt) {
                    int p = (cb << 6) + nt * 16 + col;
                    float w = weightf<SEL>(p, tq[g], mk0[g], mk1[g]);
                    if (w > 0.0f) cm = fmaxf(cm, sv[nt][g]);
                }
                cm = fmaxf(cm, __shfl_xor(cm, 1));
                cm = fmaxf(cm, __shfl_xor(cm, 2));
                cm = fmaxf(cm, __shfl_xor(cm, 4));
                cm = fmaxf(cm, __shfl_xor(cm, 8));
                float nM = fmaxf(M[g], cm);
                float sc_ = expf(M[g] - nM);
                l[g] *= sc_;
                M[g] = nM;
                #pragma unroll
                for (int nt = 0; nt < 4; ++nt) O[nt][g] *= sc_;
            }
            #pragma unroll
            for (int nt = 0; nt < 4; ++nt) {
                #pragma unroll
                for (int g = 0; g < 4; ++g) {
                    int p = (cb << 6) + nt * 16 + col;
                    float w = weightf<SEL>(p, tq[g], mk0[g], mk1[g]);
                    float ev = (w > 0.0f) ? w * expf(sv[nt][g] - M[g]) : 0.0f;
                    l[g] += ev;
                    ps[quad * 4 + g][nt * 16 + col] = ev;
                }
            }
            float4 p0 = *(const float4*)&ps[col][quad * 8];
            float4 p1 = *(const float4*)&ps[col][quad * 8 + 4];
            float4 p2 = *(const float4*)&ps[col][32 + quad * 8];
            float4 p3 = *(const float4*)&ps[col][32 + quad * 8 + 4];
            bf16x8 ap0 = cvt8(p0, p1);
            bf16x8 ap1 = cvt8(p2, p3);
            #pragma unroll
            for (int nt = 0; nt < 4; ++nt) {
                bf16x8 bv0 = *(const bf16x8*)&vt[nt * 16 + col][quad * 8];
                bf16x8 bv1 = *(const bf16x8*)&vt[nt * 16 + col][32 + quad * 8];
                O[nt] = __builtin_amdgcn_mfma_f32_16x16x32_bf16(ap0, bv0, O[nt], 0, 0, 0);
                O[nt] = __builtin_amdgcn_mfma_f32_16x16x32_bf16(ap1, bv1, O[nt], 0, 0, 0);
            }

            if (nxt < 0) break;
            cb = nxt; rem = rem2;
        }
    }
    #pragma unroll
    for (int g = 0; g < 4; ++g) {
        l[g] += __shfl_xor(l[g], 1);
        l[g] += __shfl_xor(l[g], 2);
        l[g] += __shfl_xor(l[g], 4);
        l[g] += __shfl_xor(l[g], 8);
        float inv = 1.0f / l[g];
        #pragma unroll
        for (int nt = 0; nt < 4; ++nt) O[nt][g] *= inv;
    }
}

// ---------------------------------------------------------------------------
// Flash kernel: grid (64, 4, 2); z = branch (0=sel, 1=win). Online softmax +
// chunk skip + register prefetch. atomicAdd onto out (= g0*ocmp from nsa_cmp).
// ---------------------------------------------------------------------------
__global__ __launch_bounds__(256) void nsa_flash(
    const float* __restrict__ q, const float* __restrict__ gates_lin,
    const float* __restrict__ k_slc, const float* __restrict__ v_slc,
    const float* __restrict__ k_win, const float* __restrict__ v_win,
    const unsigned int* __restrict__ selmask_ws,
    float* __restrict__ out)
{
    const int t0 = blockIdx.x * TQ;
    const int k  = blockIdx.y;
    const int br = blockIdx.z;          // 0 = selected, 1 = window
    const int tid = threadIdx.x, lane = tid & 63, r = tid >> 6;
    const int quad = lane >> 4, col = lane & 15;

    __shared__ unsigned short qs[REP][TQ][72];
    __shared__ unsigned short ks[64][72];
    __shared__ unsigned short vt[64][88];
    __shared__ float ps[REP][TQ][76];
    __shared__ unsigned int selm[TQ][2];
    __shared__ unsigned int chunkmask_s;

    {
        int qrow = lane >> 2, dseg = lane & 3;
        const float* src = q + ((r * NKV + k) * T_LEN + t0 + qrow) * DH + dseg * 16;
        float4 a0 = *(const float4*)src,       a1 = *(const float4*)(src + 4);
        float4 a2 = *(const float4*)(src + 8), a3 = *(const float4*)(src + 12);
        *(bf16x8*)&qs[r][qrow][dseg * 16]     = cvt8(a0, a1);
        *(bf16x8*)&qs[r][qrow][dseg * 16 + 8] = cvt8(a2, a3);
    }
    if (tid < TQ) {
        selm[tid][0] = selmask_ws[(k * T_LEN + t0 + tid) * 2 + 0];
        selm[tid][1] = selmask_ws[(k * T_LEN + t0 + tid) * 2 + 1];
    }
    __syncthreads();

    if (br == 0 && tid < TQ) {
        unsigned long long mk = (unsigned long long)selm[tid][0]
                              | ((unsigned long long)selm[tid][1] << 32);
        unsigned cm = 0;
        #pragma unroll
        for (int m2 = 0; m2 < 16; ++m2) {
            unsigned nib = (unsigned)((mk >> (4 * m2)) & 0xFull);
            if (nib) cm |= 1u << m2;
            if (nib & 8u) cm |= 1u << (m2 + 1);
        }
        cm |= __shfl_xor(cm, 1); cm |= __shfl_xor(cm, 2);
        cm |= __shfl_xor(cm, 4); cm |= __shfl_xor(cm, 8);
        if (tid == 0) chunkmask_s = cm;
    }
    __syncthreads();

    bf16x8 qf0 = *(const bf16x8*)&qs[r][col][quad * 8];
    bf16x8 qf1 = *(const bf16x8*)&qs[r][col][32 + quad * 8];

    const int tmax = t0 + TQ - 1;
    f32x4 O[4];
    if (br == 0) {
        flash_branch<true>(k_slc, v_slc, k, t0, 0, tmax >> 6, chunkmask_s,
                           tid, quad, col, qf0, qf1, ks, vt, ps[r], selm, O);
    } else {
        int wlo = t0 - 255; if (wlo < 0) wlo = 0;
        flash_branch<false>(k_win, v_win, k, t0, wlo >> 6, tmax >> 6, 0xFFFFFFFFu,
                            tid, quad, col, qf0, qf1, ks, vt, ps[r], selm, O);
    }

    const int hq = r * NKV + k;
    #pragma unroll
    for (int g = 0; g < 4; ++g) {
        int tq = t0 + quad * 4 + g;
        float gg = sigmoidf(gates_lin[tq * 48 + hq * 3 + 1 + br]);
        #pragma unroll
        for (int nt = 0; nt < 4; ++nt) {
            int d = nt * 16 + col;
            atomicAdd(&out[(hq * T_LEN + tq) * DH + d], gg * O[nt][g]);
        }
    }
}

extern "C" void kernel_launch(void* const* d_in, const int* in_sizes, int n_in,
                              void* d_out, int out_size, void* d_ws, size_t ws_size,
                              hipStream_t stream) {
    const float* x         = (const float*)d_in[0];
    const float* q         = (const float*)d_in[1];
    const float* gate_w    = (const float*)d_in[2];
    const float* gate_b    = (const float*)d_in[3];
    const float* wk_cmp    = (const float*)d_in[4];
    const float* wv_cmp    = (const float*)d_in[5];
    const float* wk_slc    = (const float*)d_in[6];
    const float* wv_slc    = (const float*)d_in[7];
    const float* wk_win    = (const float*)d_in[8];
    const float* wv_win    = (const float*)d_in[9];
    const float* block_pos = (const float*)d_in[10];
    const float* ck1_w     = (const float*)d_in[11];
    const float* ck1_b     = (const float*)d_in[12];
    const float* ck2_w     = (const float*)d_in[13];
    const float* ck2_b     = (const float*)d_in[14];
    const float* cv1_w     = (const float*)d_in[15];
    const float* cv1_b     = (const float*)d_in[16];
    const float* cv2_w     = (const float*)d_in[17];
    const float* cv2_b     = (const float*)d_in[18];
    float* out = (float*)d_out;

    float* ws = (float*)d_ws;
    float* gates_lin = ws;                         // 1024*48
    float* k_cmp = gates_lin + T_LEN * 48;         // 1024*256 each
    float* v_cmp = k_cmp + T_LEN * KVD;
    float* k_slc = v_cmp + T_LEN * KVD;
    float* v_slc = k_slc + T_LEN * KVD;
    float* k_win = v_slc + T_LEN * KVD;
    float* v_win = k_win + T_LEN * KVD;
    float* ksum  = v_win + T_LEN * KVD;            // 63*4*64 each
    float* vsum  = ksum + NB * KVD;
    unsigned int* selmask_ws = (unsigned int*)(vsum + NB * KVD); // 4*1024*2

    dim3 blk(256);
    size_t smem_bytes = 2 * 32 * 68 * sizeof(float);
    proj_all<<<dim3(25, 16), blk, smem_bytes, stream>>>(
        x, gate_w, gate_b, wk_cmp, wv_cmp, wk_slc, wv_slc, wk_win, wv_win,
        gates_lin, k_cmp, v_cmp, k_slc, v_slc, k_win, v_win);
    nsa_summarize<<<dim3(16, NKV, 2), blk, 0, stream>>>(
        k_cmp, v_cmp, block_pos,
        ck1_w, ck1_b, ck2_w, ck2_b, cv1_w, cv1_b, cv2_w, cv2_b,
        ksum, vsum);
    nsa_cmp<<<dim3(T_LEN / T4, NKV), blk, 0, stream>>>(
        q, gates_lin, ksum, vsum, out, selmask_ws);
    nsa_flash<<<dim3(T_LEN / TQ, NKV, 2), blk, 0, stream>>>(
        q, gates_lin, k_slc, v_slc, k_win, v_win, selmask_ws, out);
}